// Round 7
// baseline (1602.332 us; speedup 1.0000x reference)
//
#include <hip/hip_runtime.h>

#define DEV __device__ __forceinline__

using short8 = __attribute__((ext_vector_type(8))) short;
using f32x4  = __attribute__((ext_vector_type(4))) float;
using i32x4  = __attribute__((ext_vector_type(4))) int;

DEV float b2f(short s) {
  union { unsigned u; float f; } c;
  c.u = ((unsigned)(unsigned short)s) << 16;
  return c.f;
}
DEV short f2b(float f) {
  union { float f; unsigned u; } c; c.f = f;
  unsigned u = c.u + 0x7fffu + ((c.u >> 16) & 1u);
  return (short)(u >> 16);
}
DEV float fast_sigmoid(float x) {   // rcp+exp: ~20 cyc vs ~90 for fp32 divide
  return __builtin_amdgcn_rcpf(1.f + __expf(-x));
}
DEV float fast_tanh(float x) {      // 1 - 2/(e^2x+1); saturates correctly at +-inf
  return 1.f - 2.f * __builtin_amdgcn_rcpf(1.f + __expf(2.f * x));
}
// async global->LDS, 16B per lane. LDS dest = uniform base + lane*16.
DEV void async_ld16(const void* g, void* lds) {
  __builtin_amdgcn_global_load_lds(
      (const __attribute__((address_space(1))) void*)(unsigned long long)g,
      (__attribute__((address_space(3))) void*)(unsigned)(unsigned long long)lds,
      16, 0, 0);
}

// ---------------- fp32 -> bf16 convert: w_ih_f, w_ih_b ----------------
__global__ __launch_bounds__(256) void k_cvt2(const float* __restrict__ a, const float* __restrict__ b,
                                              short* __restrict__ oa, short* __restrict__ ob) {
  int blk = blockIdx.x;
  const float* in; short* out; int base;
  if (blk < 384) { in = a; out = oa; base = blk; }
  else           { in = b; out = ob; base = blk - 384; }
  int i = base * 256 + threadIdx.x;
  f32x4 v = *(const f32x4*)(in + (size_t)i * 4);
  short4 o;
#pragma unroll
  for (int j = 0; j < 4; j++) ((short*)&o)[j] = f2b(v[j]);
  *(short4*)(out + (size_t)i * 4) = o;
}

// ---------------- w_hh fp32 -> i8 B-fragments (scale 256) ----------------
// out[d][v(16)][g(3)][c(4)][lane(64)] : 16 bytes = B[n=lane&15][k=c*64+(lane>>4)*16+j]
__global__ __launch_bounds__(256) void k_wq8(const float* __restrict__ wf,
                                             const float* __restrict__ wb,
                                             int* __restrict__ out) {
  int flat = blockIdx.x * 256 + threadIdx.x;   // 24576 total (96 blocks)
  int lane = flat & 63;
  int c = (flat >> 6) & 3;
  int t = flat >> 8;
  int g = t % 3;
  int t2 = t / 3;
  int v = t2 & 15, d = t2 >> 4;
  const float* w = d ? wb : wf;
  int row = g * 256 + v * 16 + (lane & 15);
  int k0 = c * 64 + (lane >> 4) * 16;
  const float* p = w + (size_t)row * 256 + k0;
  int pk[4];
#pragma unroll
  for (int i = 0; i < 4; i++) {
    f32x4 f = *(const f32x4*)(p + i * 4);
    int b0 = (int)__builtin_rintf(f[0] * 256.f);
    int b1 = (int)__builtin_rintf(f[1] * 256.f);
    int b2 = (int)__builtin_rintf(f[2] * 256.f);
    int b3 = (int)__builtin_rintf(f[3] * 256.f);
    b0 = min(127, max(-127, b0)); b1 = min(127, max(-127, b1));
    b2 = min(127, max(-127, b2)); b3 = min(127, max(-127, b3));
    pk[i] = (b0 & 255) | ((b1 & 255) << 8) | ((b2 & 255) << 16) | ((b3 & 255) << 24);
  }
  *(int4*)(out + (size_t)flat * 4) = *(int4*)pk;
}

// ---------------- embed + positional encoding (fp32 W -> bf16 h0) ----------------
__global__ __launch_bounds__(256) void k_embed(const int* __restrict__ x,
                                               const float* __restrict__ W,
                                               short* __restrict__ h0) {
  int flat = blockIdx.x * 256 + threadIdx.x;   // 0 .. 1048575 (B*T*E/8)
  int row  = flat >> 6;                        // b*T + t
  int e0   = (flat & 63) << 3;
  int tok  = x[row];
  int t    = row & 511;
  const float* wp = W + (size_t)tok * 512 + e0;
  float v[8];
  *(f32x4*)v       = *(const f32x4*)(wp);
  *(f32x4*)(v + 4) = *(const f32x4*)(wp + 4);
  short8 o;
#pragma unroll
  for (int i = 0; i < 8; i += 2) {
    float f = expf(-9.210340371976184f * (float)(e0 + i) * (1.f / 512.f));
    float ang = (float)t * f;
    o[i]     = f2b(v[i]     + sinf(ang));
    o[i + 1] = f2b(v[i + 1] + cosf(ang));
  }
  *(short8*)(h0 + (size_t)flat * 8) = o;
}

// ---------------- 128x128 MFMA GEMM, A(M,K) bf16 * B(N,K) bf16 ----------------
// Operand-SWAPPED MFMA (mfma(bf,af) computes C^T fragments): lane l, reg r =
// C[bm*128+wm*64+i*16+(l&15)][bn*128+wn*64+j*16+(l>>4)*4+r] -> each lane's 4
// acc regs are 4 CONSECUTIVE output columns at one row -> short4/f32x4 stores
// (16 store instrs/wave vs 64 scalar) and f32x4 bias loads. Exact: A and B
// 16x16 lane->k maps are mirror-identical, so the operand swap is bit-exact.
// MODE 1: bf16 out + bias + relu. MODE 4: bf16 out + bias.
// MODE 3: bf16 out + two biases (cols<768 -> bias, else bias2), written to
//         merged gi16 layout [t][b][1536] (M rows are b*512+t). Blocks >= 1536
//         of the MODE-3 launch instead run fp32->bf16 weight transposes
//         (ff_w1/ff_w2) on otherwise-idle CUs.
// All gemm grids are %8==0 -> bijective XCD swizzle for L2 panel locality.
// Shared: 32 KB = smA (8192 shorts, 16 KB) + smB (8192 shorts) -- SAME as the
// measured round-3/4 layout. (Round-5/6 bug: smB at +4096 SHORTS = +8 KB
// overlapped smA's upper half -> absmax 841. Units: chunk = 512 shorts, 16
// chunks per matrix.)
template <int MODE>
__global__ __launch_bounds__(256) void k_gemm(const short* __restrict__ A,
    const short* __restrict__ B, const float* __restrict__ bias,
    const float* __restrict__ bias2,
    float* __restrict__ Cf, short* __restrict__ Cb, int M, int N, int K,
    const float* __restrict__ tw1, const float* __restrict__ tw2,
    short* __restrict__ w1t, short* __restrict__ w2t) {
  __shared__ __align__(16) char smem[32768];
  short* smA = (short*)smem;
  short* smB = (short*)smem + 8192;
  const int blk0 = blockIdx.x;

  if (MODE == 3 && blk0 >= 1536) {
    // ---- folded transcvt: one 32x32 fp32->bf16 transpose tile per block ----
    int tileid = blk0 - 1536;                  // 0..8191
    const float* in; short* out; int R, C, tm;
    if (tileid < 4096) { int mat = tileid >> 10; in = tw1 + (size_t)mat * 1048576;
                         out = w1t + (size_t)mat * 1048576; R = 512; C = 2048; tm = tileid & 1023; }
    else               { int mat = (tileid - 4096) >> 10; in = tw2 + (size_t)mat * 1048576;
                         out = w2t + (size_t)mat * 1048576; R = 2048; C = 512; tm = tileid & 1023; }
    float (*tile)[33] = (float(*)[33])smem;
    int ct = C >> 5;
    int bc = tm % ct, br = tm / ct;
    int r0 = br << 5, c0 = bc << 5;
    for (int i = threadIdx.x; i < 1024; i += 256) {
      int r = i >> 5, c = i & 31;
      tile[r][c] = in[(size_t)(r0 + r) * C + c0 + c];
    }
    __syncthreads();
    for (int i = threadIdx.x; i < 1024; i += 256) {
      int c = i >> 5, r = i & 31;
      out[(size_t)(c0 + c) * R + r0 + r] = f2b(tile[r][c]);
    }
    return;
  }

  const int ngemm = (MODE == 3) ? 1536 : gridDim.x;
  const int blk = (blk0 % 8) * (ngemm >> 3) + (blk0 >> 3);   // XCD swizzle
  const int tid = threadIdx.x, lane = tid & 63, wave = tid >> 6;
  const int m15 = lane & 15, quad = lane >> 4, q8 = quad << 3;
  const int tn = N >> 7;
  const int bm = blk / tn, bn = blk % tn;
  const int wm = wave & 1, wn = wave >> 1;
  const f32x4 z4 = {0.f, 0.f, 0.f, 0.f};
  f32x4 acc[4][4];
#pragma unroll
  for (int i = 0; i < 4; i++)
#pragma unroll
    for (int j = 0; j < 4; j++) acc[i][j] = z4;

  for (int k0 = 0; k0 < K; k0 += 64) {
#pragma unroll
    for (int is = 0; is < 4; is++) {
      int c = is * 4 + wave;
      int mb = c & 7, kb = c >> 3;
      async_ld16(A + (size_t)(bm * 128 + mb * 16 + m15) * K + k0 + kb * 32 + q8, smA + c * 512);
      async_ld16(B + (size_t)(bn * 128 + mb * 16 + m15) * K + k0 + kb * 32 + q8, smB + c * 512);
    }
    __syncthreads();
#pragma unroll
    for (int kk = 0; kk < 2; kk++) {
      short8 af[4], bf[4];
#pragma unroll
      for (int i = 0; i < 4; i++)
        af[i] = *(const short8*)(smA + (kk * 8 + wm * 4 + i) * 512 + lane * 8);
#pragma unroll
      for (int j = 0; j < 4; j++)
        bf[j] = *(const short8*)(smB + (kk * 8 + wn * 4 + j) * 512 + lane * 8);
#pragma unroll
      for (int i = 0; i < 4; i++)
#pragma unroll
        for (int j = 0; j < 4; j++)
          acc[i][j] = __builtin_amdgcn_mfma_f32_16x16x32_bf16(bf[j], af[i], acc[i][j], 0, 0, 0);
    }
    __syncthreads();
  }
  // Swapped C^T fragment: value(row_out, col_out) with
  //   row_out = bm*128 + wm*64 + i*16 + m15   (lane&15 picks the row)
  //   col_out = bn*128 + wn*64 + j*16 + quad*4 + r  (4 consecutive cols/lane)
#pragma unroll
  for (int j = 0; j < 4; j++) {
    int col0 = bn * 128 + wn * 64 + j * 16 + quad * 4;
    f32x4 bv4;
    if (MODE == 3) {
      const float* bp = (col0 < 768) ? (bias + col0) : (bias2 + (col0 - 768));
      bv4 = *(const f32x4*)bp;
    } else {
      bv4 = *(const f32x4*)(bias + col0);
    }
#pragma unroll
    for (int i = 0; i < 4; i++) {
      int row = bm * 128 + wm * 64 + i * 16 + m15;
      f32x4 v;
#pragma unroll
      for (int r = 0; r < 4; r++) v[r] = acc[i][j][r] + bv4[r];
      if (MODE == 1 || MODE == 4) {
        short4 o;
#pragma unroll
        for (int r = 0; r < 4; r++) {
          float x = v[r];
          if (MODE == 1 && x < 0.f) x = 0.f;
          ((short*)&o)[r] = f2b(x);
        }
        *(short4*)(Cb + (size_t)row * N + col0) = o;
      } else if (MODE == 3) {
        short4 o;
#pragma unroll
        for (int r = 0; r < 4; r++) ((short*)&o)[r] = f2b(v[r]);
        // merged gi16: [t][b][1536], row = b*512 + t
        *(short4*)(Cb + ((size_t)((row & 511) * 32 + (row >> 9))) * 1536 + col0) = o;
      } else {
        *(f32x4*)(Cf + (size_t)row * N + col0) = v;
      }
    }
  }
}

// ---------------- bidirectional GRU v8: i8 K=64 MFMA, bpermute exchange ----------------
// 16 blocks (d = blk&1, bg = blk>>1 -> 4 batch rows), 1024 thr. (transcvt fold
// REMOVED -- it contended for L2/HBM with the GRU's gi streaming, +33us.)
// Phase A: 12 mfma_i32_16x16x64_i8. Exchange: 12 ds_bpermute + selects.
// The ONLY barrier protects the hb double buffer.
__global__ __launch_bounds__(1024) void k_gru(
    const int* __restrict__ wq8,
    const float* __restrict__ bhh_f, const float* __restrict__ bhh_b,
    const short* __restrict__ gi16,      // merged [t][b][1536]
    short* __restrict__ hcat16) {
  __shared__ __align__(16) char hb[2][4096];   // i8 h: [row16][256] swizzled
  const int blk = blockIdx.x;
  const int d = blk & 1, bg = blk >> 1;
  const int tid = threadIdx.x, lane = tid & 63, v = tid >> 6;
  const int m15 = lane & 15, quad = lane >> 4;
  const int col = v * 16 + m15;        // this lane's h column
  const int brow = quad;               // this lane's local batch row (0..3)
  const float* bhh = d ? bhh_b : bhh_f;
  const float SCL = 1.f / (127.f * 256.f);

  // B fragments (i8): per-(d,v) stride = 3*4*64 i32x4 entries
  i32x4 Bq[3][4];
  {
    const i32x4* wp = (const i32x4*)wq8 + (size_t)(d * 16 + v) * (3 * 4 * 64);
#pragma unroll
    for (int g = 0; g < 3; g++)
#pragma unroll
      for (int c = 0; c < 4; c++)
        Bq[g][c] = wp[(g * 4 + c) * 64 + lane];
  }
  float bh[3];
#pragma unroll
  for (int g = 0; g < 3; g++) bh[g] = bhh[g * 256 + col];

  // A-read offsets (loop-invariant): 4x b128 per lane, conflict-free
  const int sw = (m15 & 7) << 4;
  const int aof0 = m15 * 256 + ((quad * 16 +   0) ^ sw);
  const int aof1 = m15 * 256 + ((quad * 16 +  64) ^ sw);
  const int aof2 = m15 * 256 + ((quad * 16 + 128) ^ sw);
  const int aof3 = m15 * 256 + ((quad * 16 + 192) ^ sw);
  // h-write offset: row=brow, k=col (linear k layout, chunk-swizzled)
  const int wofs = brow * 256 + (col ^ (brow << 4));
  const int idx4 = m15 << 2;           // bpermute source index

  // zero both h buffers (rows 4..15 stay zero forever)
  for (int i = tid; i < 2048; i += 1024) ((int*)hb)[i] = 0;

  const int t0 = d ? 511 : 0;
  const long gdelta = (long)(d ? -1 : 1) * 32 * 1536;
  const long hdelta = (long)(d ? -1 : 1) * 32 * 512;
  const short* gp = gi16 + ((size_t)t0 * 32 + bg * 4 + brow) * 1536 + d * 768 + col;
  short* hflush = hcat16 + ((size_t)t0 * 32 + bg * 4 + brow) * 512 + d * 256 + col;

  float gic0 = b2f(gp[0]), gic1 = b2f(gp[256]), gic2 = b2f(gp[512]);
  gp += gdelta;
  float hprev = 0.f;
  unsigned obuf[4] = {0u, 0u, 0u, 0u};
  const i32x4 zi = {0, 0, 0, 0};
  __syncthreads();   // hb zero visible

  for (int s = 0; s < 512; s++) {
    // flush previous 8 h outputs at TOP of step: stores drain at this step's
    // end barrier, hidden under phase A instead of serial before it.
    if ((s & 7) == 0 && s) {
      short* p = hflush;
#pragma unroll
      for (int k = 0; k < 8; k++) {
        *p = (short)(obuf[k >> 1] >> ((k & 1) * 16));
        p += hdelta;
      }
      hflush += 8 * hdelta;
    }
    // next step's gi loads (hide L2/HBM latency under phase A)
    short n0 = 0, n1 = 0, n2 = 0;
    if (s < 511) {
      n0 = gp[0]; n1 = gp[256]; n2 = gp[512];
      gp += gdelta;
    }
    // ---- phase A: gh = h[s] @ w_hh^T (4x conflict-free ds_read_b128) ----
    const char* hs = hb[s & 1];
    i32x4 Af0 = *(const i32x4*)(hs + aof0);
    i32x4 Af1 = *(const i32x4*)(hs + aof1);
    i32x4 Af2 = *(const i32x4*)(hs + aof2);
    i32x4 Af3 = *(const i32x4*)(hs + aof3);
    i32x4 acc0 = zi, acc1 = zi, acc2 = zi;
    acc0 = __builtin_amdgcn_mfma_i32_16x16x64_i8(Af0, Bq[0][0], acc0, 0, 0, 0);
    acc1 = __builtin_amdgcn_mfma_i32_16x16x64_i8(Af0, Bq[1][0], acc1, 0, 0, 0);
    acc2 = __builtin_amdgcn_mfma_i32_16x16x64_i8(Af0, Bq[2][0], acc2, 0, 0, 0);
    acc0 = __builtin_amdgcn_mfma_i32_16x16x64_i8(Af1, Bq[0][1], acc0, 0, 0, 0);
    acc1 = __builtin_amdgcn_mfma_i32_16x16x64_i8(Af1, Bq[1][1], acc1, 0, 0, 0);
    acc2 = __builtin_amdgcn_mfma_i32_16x16x64_i8(Af1, Bq[2][1], acc2, 0, 0, 0);
    acc0 = __builtin_amdgcn_mfma_i32_16x16x64_i8(Af2, Bq[0][2], acc0, 0, 0, 0);
    acc1 = __builtin_amdgcn_mfma_i32_16x16x64_i8(Af2, Bq[1][2], acc1, 0, 0, 0);
    acc2 = __builtin_amdgcn_mfma_i32_16x16x64_i8(Af2, Bq[2][2], acc2, 0, 0, 0);
    acc0 = __builtin_amdgcn_mfma_i32_16x16x64_i8(Af3, Bq[0][3], acc0, 0, 0, 0);
    acc1 = __builtin_amdgcn_mfma_i32_16x16x64_i8(Af3, Bq[1][3], acc1, 0, 0, 0);
    acc2 = __builtin_amdgcn_mfma_i32_16x16x64_i8(Af3, Bq[2][3], acc2, 0, 0, 0);
    // ---- gate exchange: ds_bpermute from lanes 0..15 (rows 0..3 in regs) ----
    int r0 = __builtin_amdgcn_ds_bpermute(idx4, acc0[0]);
    int r1 = __builtin_amdgcn_ds_bpermute(idx4, acc0[1]);
    int r2 = __builtin_amdgcn_ds_bpermute(idx4, acc0[2]);
    int r3 = __builtin_amdgcn_ds_bpermute(idx4, acc0[3]);
    int z0 = __builtin_amdgcn_ds_bpermute(idx4, acc1[0]);
    int z1 = __builtin_amdgcn_ds_bpermute(idx4, acc1[1]);
    int z2 = __builtin_amdgcn_ds_bpermute(idx4, acc1[2]);
    int z3 = __builtin_amdgcn_ds_bpermute(idx4, acc1[3]);
    int n0i = __builtin_amdgcn_ds_bpermute(idx4, acc2[0]);
    int n1i = __builtin_amdgcn_ds_bpermute(idx4, acc2[1]);
    int n2i = __builtin_amdgcn_ds_bpermute(idx4, acc2[2]);
    int n3i = __builtin_amdgcn_ds_bpermute(idx4, acc2[3]);
    int igr = (quad & 2) ? ((quad & 1) ? r3 : r2) : ((quad & 1) ? r1 : r0);
    int igz = (quad & 2) ? ((quad & 1) ? z3 : z2) : ((quad & 1) ? z1 : z0);
    int ign = (quad & 2) ? ((quad & 1) ? n3i : n2i) : ((quad & 1) ? n1i : n0i);
    // ---- phase B: gates, 1 element/lane ----
    float r = fast_sigmoid(fmaf((float)igr, SCL, gic0 + bh[0]));
    float z = fast_sigmoid(fmaf((float)igz, SCL, gic1 + bh[1]));
    float n = fast_tanh(fmaf(r, fmaf((float)ign, SCL, bh[2]), gic2));
    float h = (1.f - z) * n + z * hprev;
    hprev = h;
    // h -> i8 LDS (swizzled layout) for next step
    int hq = (int)__builtin_rintf(h * 127.f);
    hb[(s + 1) & 1][wofs] = (char)hq;
    // buffer bf16 output (flushed at top of step s+1 when 8 accumulated)
    unsigned hb16 = (unsigned)(unsigned short)f2b(h);
    int idx = s & 7;
    if ((idx & 1) == 0) obuf[idx >> 1] = hb16;
    else                obuf[idx >> 1] |= hb16 << 16;
    gic0 = b2f(n0); gic1 = b2f(n1); gic2 = b2f(n2);
    __syncthreads();   // the one barrier: publishes hb[s+1]
  }
  // final flush (steps 504..511)
  {
    short* p = hflush;
#pragma unroll
    for (int k = 0; k < 8; k++) {
      *p = (short)(obuf[k >> 1] >> ((k & 1) * 16));
      p += hdelta;
    }
  }
}

// ---------------- residual + LayerNorm (ff input now bf16) ----------------
// FIRST=1: residual read from bf16 hcat16 (GRU output); else fp32 hres.
template <int FIRST>
__global__ __launch_bounds__(256) void k_ln(const float* __restrict__ hinf,
    const short* __restrict__ ff16, const float* __restrict__ gw,
    const float* __restrict__ bw, float* __restrict__ hout, short* __restrict__ h16) {
  int row = blockIdx.x * 4 + (threadIdx.x >> 6);
  int lane = threadIdx.x & 63;
  size_t base = (size_t)row * 512 + lane * 8;
  f32x4 x0, x1;
  if (FIRST) {
    short8 hv = *(const short8*)(h16 + base);
#pragma unroll
    for (int i = 0; i < 4; i++) { x0[i] = b2f(hv[i]); x1[i] = b2f(hv[4 + i]); }
  } else {
    x0 = *(const f32x4*)(hinf + base);
    x1 = *(const f32x4*)(hinf + base + 4);
  }
  short8 fv = *(const short8*)(ff16 + base);
#pragma unroll
  for (int i = 0; i < 4; i++) { x0[i] += b2f(fv[i]); x1[i] += b2f(fv[4 + i]); }
  float s = x0[0] + x0[1] + x0[2] + x0[3] + x1[0] + x1[1] + x1[2] + x1[3];
#pragma unroll
  for (int off = 32; off >= 1; off >>= 1) s += __shfl_xor(s, off);
  float mu = s * (1.f / 512.f);
  float vv = 0.f;
#pragma unroll
  for (int i = 0; i < 4; i++) { float d0 = x0[i] - mu, d1 = x1[i] - mu; vv += d0 * d0 + d1 * d1; }
#pragma unroll
  for (int off = 32; off >= 1; off >>= 1) vv += __shfl_xor(vv, off);
  float rs = rsqrtf(vv * (1.f / 512.f) + 1e-5f);
  int e = lane * 8;
  f32x4 g0 = *(const f32x4*)(gw + e), g1 = *(const f32x4*)(gw + e + 4);
  f32x4 bb0 = *(const f32x4*)(bw + e), bb1 = *(const f32x4*)(bw + e + 4);
  f32x4 o0, o1; short8 ob;
#pragma unroll
  for (int i = 0; i < 4; i++) {
    float a = (x0[i] - mu) * rs * g0[i] + bb0[i];
    float b = (x1[i] - mu) * rs * g1[i] + bb1[i];
    o0[i] = a; o1[i] = b; ob[i] = f2b(a); ob[4 + i] = f2b(b);
  }
  *(f32x4*)(hout + base) = o0;
  *(f32x4*)(hout + base + 4) = o1;
  *(short8*)(h16 + base) = ob;
}

// ---------------- final FC (N=16), fp32 weights ----------------
__global__ __launch_bounds__(256) void k_fc(const float* __restrict__ h,
    const float* __restrict__ fcw, const float* __restrict__ bias,
    float* __restrict__ logits) {
  int row = blockIdx.x * 4 + (threadIdx.x >> 6);
  int lane = threadIdx.x & 63;
  int c = lane & 15, part = lane >> 4;
  const float* ph = h + (size_t)row * 512 + part * 128;
  const float* pw = fcw + (size_t)part * 128 * 16 + c;
  float acc = 0.f;
#pragma unroll 8
  for (int k = 0; k < 128; k += 4) {
    f32x4 hv = *(const f32x4*)(ph + k);
    acc += hv[0] * pw[(k) * 16] + hv[1] * pw[(k + 1) * 16]
         + hv[2] * pw[(k + 2) * 16] + hv[3] * pw[(k + 3) * 16];
  }
  acc += __shfl_xor(acc, 16);
  acc += __shfl_xor(acc, 32);
  if (part == 0) logits[(size_t)row * 16 + c] = acc + bias[c];
}

// ---------------- CRF Viterbi v2: wave-parallel max-plus ----------------
__global__ __launch_bounds__(64) void k_crf(const float* __restrict__ logits,
    const int* __restrict__ y, const float* __restrict__ trans,
    float* __restrict__ out) {
  __shared__ unsigned char bp[511][16];
  int b = blockIdx.x, lane = threadIdx.x;
  int cur = lane & 15, g = lane >> 4;
  float trr0 = trans[(4 * g + 0) * 16 + cur];
  float trr1 = trans[(4 * g + 1) * 16 + cur];
  float trr2 = trans[(4 * g + 2) * 16 + cur];
  float trr3 = trans[(4 * g + 3) * 16 + cur];
  const float* lg = logits + (size_t)b * 16;
  const int* yb = y + b * 512;
  float score = trans[16 + cur] + lg[cur];    // tr[BOS=1][cur] + emit[0]
  float e_next = lg[512 + cur];
  int y_next = yb[1];
  for (int t = 1; t < 512; t++) {
    float e = e_next; int ym = y_next;
    if (t < 511) { e_next = lg[(t + 1) * 512 + cur]; y_next = yb[t + 1]; }
    float s0 = __shfl(score, 4 * g + 0);
    float s1 = __shfl(score, 4 * g + 1);
    float s2 = __shfl(score, 4 * g + 2);
    float s3 = __shfl(score, 4 * g + 3);
    float best = s0 + trr0; int arg = 4 * g;
    float c1 = s1 + trr1; if (c1 > best) { best = c1; arg = 4 * g + 1; }
    float c2 = s2 + trr2; if (c2 > best) { best = c2; arg = 4 * g + 2; }
    float c3 = s3 + trr3; if (c3 > best) { best = c3; arg = 4 * g + 3; }
    float pv = __shfl_xor(best, 16); int pa = __shfl_xor(arg, 16);
    bool take = (lane & 16) ? (pv >= best) : (pv > best);
    if (take) { best = pv; arg = pa; }
    pv = __shfl_xor(best, 32); pa = __shfl_xor(arg, 32);
    take = (lane & 32) ? (pv >= best) : (pv > best);
    if (take) { best = pv; arg = pa; }
    if (lane < 16) bp[t - 1][cur] = (unsigned char)arg;
    float ns = best + e;
    if (ym == 0) ns = score;
    score = ns;
  }
  score += trans[cur * 16 + 2];               // tr[cur][EOS=2]
  float best = -3.4e38f; int argb = 0;
#pragma unroll
  for (int p = 0; p < 16; p++) {
    float sp = __shfl(score, p);
    if (sp > best) { best = sp; argb = p; }
  }
  __syncthreads();
  if (lane == 0) {
    out[b] = best;
    float* po = out + 32 + (size_t)b * 512;
    int tag = argb;
    po[511] = (float)tag;
    for (int t = 511; t >= 1; t--) {
      int prev = bp[t - 1][tag];
      if (yb[t] == 0) prev = tag;
      po[t - 1] = (float)prev;
      tag = prev;
    }
  }
}

// ---------------- host ----------------
extern "C" void kernel_launch(void* const* d_in, const int* in_sizes, int n_in,
                              void* d_out, int out_size, void* d_ws, size_t ws_size,
                              hipStream_t stream) {
  const int*   x      = (const int*)d_in[0];
  const int*   y      = (const int*)d_in[1];
  const float* embedW = (const float*)d_in[2];
  const float* w_ih_f = (const float*)d_in[3];
  const float* w_hh_f = (const float*)d_in[4];
  const float* b_ih_f = (const float*)d_in[5];
  const float* b_hh_f = (const float*)d_in[6];
  const float* w_ih_b = (const float*)d_in[7];
  const float* w_hh_b = (const float*)d_in[8];
  const float* b_ih_b = (const float*)d_in[9];
  const float* b_hh_b = (const float*)d_in[10];
  const float* ff_w1  = (const float*)d_in[11];
  const float* ff_b1  = (const float*)d_in[12];
  const float* ff_w2  = (const float*)d_in[13];
  const float* ff_b2  = (const float*)d_in[14];
  const float* ln_g   = (const float*)d_in[15];
  const float* ln_b   = (const float*)d_in[16];
  const float* fc_w   = (const float*)d_in[17];
  const float* fc_b   = (const float*)d_in[18];
  const float* trans  = (const float*)d_in[19];
  float* out = (float*)d_out;

  char* ws = (char*)d_ws;
  short* h0     = (short*)(ws + 0);                 // 16.78 MB bf16 (B,T,E)
  short* gi16   = (short*)(ws + 16777216);          // 50.33 MB bf16 [t][b][1536] (f|b)
  short* mid    = (short*)(ws + 16777216);          // 67.1 MB bf16, overlays gi16 (dead after GRU)
  short* ffout16= (short*)(ws + 83886080);          // 16.78 MB bf16 FF output
  short* wihf16 = (short*)(ws + 117440512);         // bf16 (768,512); wihb16 contiguous after
  short* wihb16 = (short*)(ws + 118226944);         //   -> combined (1536,512) B matrix
  int*   wq8    = (int*)  (ws + 119013376);         // i8 frags, 393216 B
  short* w1t    = (short*)(ws + 119799808);         // bf16 (4 x 2048x512)
  short* w2t    = (short*)(ws + 128188416);         // bf16 (4 x 512x2048)
  short* hcat16 = (short*)(ws + 136577024);         // bf16 [t][b][512]
  float* hres   = (float*)(ws + 153354240);         // fp32 residual [t][b][512]
  float* logits = (float*)(ws + 186908672);         // fp32 [t][b][16]

  k_embed<<<4096, 256, 0, stream>>>(x, embedW, h0);
  k_cvt2<<<768, 256, 0, stream>>>(w_ih_f, w_ih_b, wihf16, wihb16);
  k_wq8<<<96, 256, 0, stream>>>(w_hh_f, w_hh_b, wq8);

  // merged ih-projection (blocks 0..1535) + folded ff-weight transposes
  k_gemm<3><<<9728, 256, 0, stream>>>(h0, wihf16, b_ih_f, b_ih_b, nullptr, gi16,
                                      16384, 1536, 512, ff_w1, ff_w2, w1t, w2t);

  k_gru<<<16, 1024, 0, stream>>>(wq8, b_hh_f, b_hh_b, gi16, hcat16);

  for (int i = 0; i < 4; i++) {
    k_gemm<1><<<2048, 256, 0, stream>>>(hcat16, w1t + (size_t)i * 1048576, ff_b1 + i * 2048,
                                        nullptr, nullptr, mid, 16384, 2048, 512,
                                        nullptr, nullptr, nullptr, nullptr);
    k_gemm<4><<<512, 256, 0, stream>>>(mid, w2t + (size_t)i * 1048576, ff_b2 + i * 512,
                                       nullptr, nullptr, ffout16, 16384, 512, 2048,
                                       nullptr, nullptr, nullptr, nullptr);
    if (i == 0)
      k_ln<1><<<4096, 256, 0, stream>>>(nullptr, ffout16, ln_g, ln_b, hres, hcat16);
    else
      k_ln<0><<<4096, 256, 0, stream>>>(hres, ffout16, ln_g + i * 512, ln_b + i * 512, hres, hcat16);
  }
  k_fc<<<4096, 256, 0, stream>>>(hres, fc_w, fc_b, logits);
  k_crf<<<32, 64, 0, stream>>>(logits, y, trans, out);
}

// Round 8
// 1525.839 us; speedup vs baseline: 1.0501x; 1.0501x over previous
//
#include <hip/hip_runtime.h>

#define DEV __device__ __forceinline__

using short8 = __attribute__((ext_vector_type(8))) short;
using f32x4  = __attribute__((ext_vector_type(4))) float;
using i32x4  = __attribute__((ext_vector_type(4))) int;

DEV float b2f(short s) {
  union { unsigned u; float f; } c;
  c.u = ((unsigned)(unsigned short)s) << 16;
  return c.f;
}
DEV short f2b(float f) {
  union { float f; unsigned u; } c; c.f = f;
  unsigned u = c.u + 0x7fffu + ((c.u >> 16) & 1u);
  return (short)(u >> 16);
}
DEV float fast_sigmoid(float x) {   // rcp+exp: ~20 cyc vs ~90 for fp32 divide
  return __builtin_amdgcn_rcpf(1.f + __expf(-x));
}
DEV float fast_tanh(float x) {      // 1 - 2/(e^2x+1); saturates correctly at +-inf
  return 1.f - 2.f * __builtin_amdgcn_rcpf(1.f + __expf(2.f * x));
}
// async global->LDS, 16B per lane. LDS dest = uniform base + lane*16.
DEV void async_ld16(const void* g, void* lds) {
  __builtin_amdgcn_global_load_lds(
      (const __attribute__((address_space(1))) void*)(unsigned long long)g,
      (__attribute__((address_space(3))) void*)(unsigned)(unsigned long long)lds,
      16, 0, 0);
}

// ---------------- fp32 -> bf16 convert: w_ih_f, w_ih_b ----------------
__global__ __launch_bounds__(256) void k_cvt2(const float* __restrict__ a, const float* __restrict__ b,
                                              short* __restrict__ oa, short* __restrict__ ob) {
  int blk = blockIdx.x;
  const float* in; short* out; int base;
  if (blk < 384) { in = a; out = oa; base = blk; }
  else           { in = b; out = ob; base = blk - 384; }
  int i = base * 256 + threadIdx.x;
  f32x4 v = *(const f32x4*)(in + (size_t)i * 4);
  short4 o;
#pragma unroll
  for (int j = 0; j < 4; j++) ((short*)&o)[j] = f2b(v[j]);
  *(short4*)(out + (size_t)i * 4) = o;
}

// ---------------- w_hh fp32 -> i8 B-fragments (scale 256) ----------------
// out[d][v(16)][g(3)][c(4)][lane(64)] : 16 bytes = B[n=lane&15][k=c*64+(lane>>4)*16+j]
__global__ __launch_bounds__(256) void k_wq8(const float* __restrict__ wf,
                                             const float* __restrict__ wb,
                                             int* __restrict__ out) {
  int flat = blockIdx.x * 256 + threadIdx.x;   // 24576 total (96 blocks)
  int lane = flat & 63;
  int c = (flat >> 6) & 3;
  int t = flat >> 8;
  int g = t % 3;
  int t2 = t / 3;
  int v = t2 & 15, d = t2 >> 4;
  const float* w = d ? wb : wf;
  int row = g * 256 + v * 16 + (lane & 15);
  int k0 = c * 64 + (lane >> 4) * 16;
  const float* p = w + (size_t)row * 256 + k0;
  int pk[4];
#pragma unroll
  for (int i = 0; i < 4; i++) {
    f32x4 f = *(const f32x4*)(p + i * 4);
    int b0 = (int)__builtin_rintf(f[0] * 256.f);
    int b1 = (int)__builtin_rintf(f[1] * 256.f);
    int b2 = (int)__builtin_rintf(f[2] * 256.f);
    int b3 = (int)__builtin_rintf(f[3] * 256.f);
    b0 = min(127, max(-127, b0)); b1 = min(127, max(-127, b1));
    b2 = min(127, max(-127, b2)); b3 = min(127, max(-127, b3));
    pk[i] = (b0 & 255) | ((b1 & 255) << 8) | ((b2 & 255) << 16) | ((b3 & 255) << 24);
  }
  *(int4*)(out + (size_t)flat * 4) = *(int4*)pk;
}

// ---------------- embed + positional encoding (fp32 W -> bf16 h0) ----------------
__global__ __launch_bounds__(256) void k_embed(const int* __restrict__ x,
                                               const float* __restrict__ W,
                                               short* __restrict__ h0) {
  int flat = blockIdx.x * 256 + threadIdx.x;   // 0 .. 1048575 (B*T*E/8)
  int row  = flat >> 6;                        // b*T + t
  int e0   = (flat & 63) << 3;
  int tok  = x[row];
  int t    = row & 511;
  const float* wp = W + (size_t)tok * 512 + e0;
  float v[8];
  *(f32x4*)v       = *(const f32x4*)(wp);
  *(f32x4*)(v + 4) = *(const f32x4*)(wp + 4);
  short8 o;
#pragma unroll
  for (int i = 0; i < 8; i += 2) {
    float f = expf(-9.210340371976184f * (float)(e0 + i) * (1.f / 512.f));
    float ang = (float)t * f;
    o[i]     = f2b(v[i]     + sinf(ang));
    o[i + 1] = f2b(v[i + 1] + cosf(ang));
  }
  *(short8*)(h0 + (size_t)flat * 8) = o;
}

// ---------------- 128x128 MFMA GEMM, A(M,K) bf16 * B(N,K) bf16 ----------------
// Operand-SWAPPED MFMA (mfma(bf,af) computes C^T fragments): lane l, reg r =
// C[bm*128+wm*64+i*16+(l&15)][bn*128+wn*64+j*16+(l>>4)*4+r] -> each lane's 4
// acc regs are 4 CONSECUTIVE output columns at one row -> short4/f32x4 stores
// (16 store instrs/wave vs 64 scalar) and f32x4 bias loads. Exact: A and B
// 16x16 lane->k maps are mirror-identical, so the operand swap is bit-exact.
// HW-verified round 7 (passed, absmax 10.0).
// MODE 1: bf16 out + bias + relu. MODE 4: bf16 out + bias.
// MODE 3: bf16 out + two biases (cols<768 -> bias, else bias2), written to
//         merged gi16 layout [t][b][1536] (M rows are b*512+t).
// NO XCD swizzle: all working sets are L3-resident; measured round 7 the
// swizzle+fold package cost ~+45us on the FF chain (guide: swizzle ~-2% when
// L3-fit). Natural dispatch order restored.
// Shared: 32 KB = smA (8192 shorts, 16 KB) + smB (8192 shorts).
template <int MODE>
__global__ __launch_bounds__(256) void k_gemm(const short* __restrict__ A,
    const short* __restrict__ B, const float* __restrict__ bias,
    const float* __restrict__ bias2,
    float* __restrict__ Cf, short* __restrict__ Cb, int M, int N, int K) {
  __shared__ __align__(16) char smem[32768];
  short* smA = (short*)smem;
  short* smB = (short*)smem + 8192;
  const int blk = blockIdx.x;
  const int tid = threadIdx.x, lane = tid & 63, wave = tid >> 6;
  const int m15 = lane & 15, quad = lane >> 4, q8 = quad << 3;
  const int tn = N >> 7;
  const int bm = blk / tn, bn = blk % tn;
  const int wm = wave & 1, wn = wave >> 1;
  const f32x4 z4 = {0.f, 0.f, 0.f, 0.f};
  f32x4 acc[4][4];
#pragma unroll
  for (int i = 0; i < 4; i++)
#pragma unroll
    for (int j = 0; j < 4; j++) acc[i][j] = z4;

  for (int k0 = 0; k0 < K; k0 += 64) {
#pragma unroll
    for (int is = 0; is < 4; is++) {
      int c = is * 4 + wave;
      int mb = c & 7, kb = c >> 3;
      async_ld16(A + (size_t)(bm * 128 + mb * 16 + m15) * K + k0 + kb * 32 + q8, smA + c * 512);
      async_ld16(B + (size_t)(bn * 128 + mb * 16 + m15) * K + k0 + kb * 32 + q8, smB + c * 512);
    }
    __syncthreads();
#pragma unroll
    for (int kk = 0; kk < 2; kk++) {
      short8 af[4], bf[4];
#pragma unroll
      for (int i = 0; i < 4; i++)
        af[i] = *(const short8*)(smA + (kk * 8 + wm * 4 + i) * 512 + lane * 8);
#pragma unroll
      for (int j = 0; j < 4; j++)
        bf[j] = *(const short8*)(smB + (kk * 8 + wn * 4 + j) * 512 + lane * 8);
#pragma unroll
      for (int i = 0; i < 4; i++)
#pragma unroll
        for (int j = 0; j < 4; j++)
          acc[i][j] = __builtin_amdgcn_mfma_f32_16x16x32_bf16(bf[j], af[i], acc[i][j], 0, 0, 0);
    }
    __syncthreads();
  }
  // Swapped C^T fragment: value(row_out, col_out) with
  //   row_out = bm*128 + wm*64 + i*16 + m15   (lane&15 picks the row)
  //   col_out = bn*128 + wn*64 + j*16 + quad*4 + r  (4 consecutive cols/lane)
#pragma unroll
  for (int j = 0; j < 4; j++) {
    int col0 = bn * 128 + wn * 64 + j * 16 + quad * 4;
    f32x4 bv4;
    if (MODE == 3) {
      const float* bp = (col0 < 768) ? (bias + col0) : (bias2 + (col0 - 768));
      bv4 = *(const f32x4*)bp;
    } else {
      bv4 = *(const f32x4*)(bias + col0);
    }
#pragma unroll
    for (int i = 0; i < 4; i++) {
      int row = bm * 128 + wm * 64 + i * 16 + m15;
      f32x4 v;
#pragma unroll
      for (int r = 0; r < 4; r++) v[r] = acc[i][j][r] + bv4[r];
      if (MODE == 1 || MODE == 4) {
        short4 o;
#pragma unroll
        for (int r = 0; r < 4; r++) {
          float x = v[r];
          if (MODE == 1 && x < 0.f) x = 0.f;
          ((short*)&o)[r] = f2b(x);
        }
        *(short4*)(Cb + (size_t)row * N + col0) = o;
      } else if (MODE == 3) {
        short4 o;
#pragma unroll
        for (int r = 0; r < 4; r++) ((short*)&o)[r] = f2b(v[r]);
        // merged gi16: [t][b][1536], row = b*512 + t
        *(short4*)(Cb + ((size_t)((row & 511) * 32 + (row >> 9))) * 1536 + col0) = o;
      } else {
        *(f32x4*)(Cf + (size_t)row * N + col0) = v;
      }
    }
  }
}

// ---------------- bidirectional GRU v9 + folded FF-weight transpose ----------------
// Blocks 0..15: GRU (d = blk&1, bg = blk>>1 -> 4 batch rows), 1024 thr.
// Blocks 16..2063: fp32->bf16 transpose of ff_w1/ff_w2 (4 tiles of 32x32 per
//   block) -- runs on the 240 CUs the GRU leaves idle. Round-7 attribution
//   correction: round 4's gru slowdown was the bpermute exchange (+36us,
//   measured clean in r7), NOT fold contention (~0) -- fold here is free.
// GRU phase A: 12 mfma_i32_16x16x64_i8. Gate exchange: smGi wave-local LDS
//   (quad-0 writes 12 ints, all lanes read 3; same-wave DS in-order, no
//   barrier) -- measured 474us in round 3 vs 510us for ds_bpermute (round 7).
// The ONLY barrier protects the hb double buffer.
__global__ __launch_bounds__(1024) void k_gru(
    const int* __restrict__ wq8,
    const float* __restrict__ bhh_f, const float* __restrict__ bhh_b,
    const short* __restrict__ gi16,      // merged [t][b][1536]
    short* __restrict__ hcat16,
    const float* __restrict__ ff_w1, const float* __restrict__ ff_w2,
    short* __restrict__ w1t, short* __restrict__ w2t) {
  __shared__ __align__(16) char smem[20992];   // gru: hb 8192 + smGi 12800; transcvt: 16896
  const int blk = blockIdx.x;
  const int tid = threadIdx.x;

  if (blk >= 16) {
    // ---- transcvt path: 4x (32x32) fp32->bf16 transpose tiles ----
    int sub = tid >> 8, stid = tid & 255;
    int tileid = (blk - 16) * 4 + sub;           // 0..8191
    const float* in; short* out; int C, R, tm;
    if (tileid < 4096) { int mat = tileid >> 10; in = ff_w1 + (size_t)mat * 1048576;
                         out = w1t + (size_t)mat * 1048576; R = 512; C = 2048; tm = tileid & 1023; }
    else               { int mat = (tileid - 4096) >> 10; in = ff_w2 + (size_t)mat * 1048576;
                         out = w2t + (size_t)mat * 1048576; R = 2048; C = 512; tm = tileid & 1023; }
    float (*tile)[33] = (float(*)[33])(smem + sub * 4224);
    int ct = C >> 5;
    int bc = tm % ct, br = tm / ct;
    int r0 = br << 5, c0 = bc << 5;
    for (int i = stid; i < 1024; i += 256) {
      int r = i >> 5, c = i & 31;
      tile[r][c] = in[(size_t)(r0 + r) * C + c0 + c];
    }
    __syncthreads();
    for (int i = stid; i < 1024; i += 256) {
      int c = i >> 5, r = i & 31;
      out[(size_t)(c0 + c) * R + r0 + r] = f2b(tile[r][c]);
    }
    return;
  }

  // ---- GRU path ----
  char (*hb)[4096] = (char(*)[4096])smem;          // i8 h: [row16][256] swizzled, x2
  int (*smGi)[200] = (int(*)[200])(smem + 8192);   // wave-private exchange
  const int d = blk & 1, bg = blk >> 1;
  const int lane = tid & 63, v = tid >> 6;
  const int m15 = lane & 15, quad = lane >> 4;
  const int col = v * 16 + m15;        // this lane's h column
  const int brow = quad;               // this lane's local batch row (0..3)
  const float* bhh = d ? bhh_b : bhh_f;
  const float SCL = 1.f / (127.f * 256.f);

  // B fragments (i8): per-(d,v) stride = 3*4*64 i32x4 entries
  i32x4 Bq[3][4];
  {
    const i32x4* wp = (const i32x4*)wq8 + (size_t)(d * 16 + v) * (3 * 4 * 64);
#pragma unroll
    for (int g = 0; g < 3; g++)
#pragma unroll
      for (int c = 0; c < 4; c++)
        Bq[g][c] = wp[(g * 4 + c) * 64 + lane];
  }
  float bh[3];
#pragma unroll
  for (int g = 0; g < 3; g++) bh[g] = bhh[g * 256 + col];

  // A-read offsets (loop-invariant): 4x b128 per lane, conflict-free
  const int sw = (m15 & 7) << 4;
  const int aof0 = m15 * 256 + ((quad * 16 +   0) ^ sw);
  const int aof1 = m15 * 256 + ((quad * 16 +  64) ^ sw);
  const int aof2 = m15 * 256 + ((quad * 16 + 128) ^ sw);
  const int aof3 = m15 * 256 + ((quad * 16 + 192) ^ sw);
  // h-write offset: row=brow, k=col (linear k layout, chunk-swizzled)
  const int wofs = brow * 256 + (col ^ (brow << 4));

  // zero both h buffers (rows 4..15 stay zero forever)
  for (int i = tid; i < 2048; i += 1024) ((int*)hb)[i] = 0;

  const int t0 = d ? 511 : 0;
  const long gdelta = (long)(d ? -1 : 1) * 32 * 1536;
  const long hdelta = (long)(d ? -1 : 1) * 32 * 512;
  const short* gp = gi16 + ((size_t)t0 * 32 + bg * 4 + brow) * 1536 + d * 768 + col;
  short* hflush = hcat16 + ((size_t)t0 * 32 + bg * 4 + brow) * 512 + d * 256 + col;

  float gic0 = b2f(gp[0]), gic1 = b2f(gp[256]), gic2 = b2f(gp[512]);
  gp += gdelta;
  float hprev = 0.f;
  unsigned obuf[4] = {0u, 0u, 0u, 0u};
  const i32x4 zi = {0, 0, 0, 0};
  __syncthreads();   // hb zero visible

  for (int s = 0; s < 512; s++) {
    // flush previous 8 h outputs at TOP of step: stores drain at this step's
    // end barrier, hidden under phase A instead of serial before it.
    if ((s & 7) == 0 && s) {
      short* p = hflush;
#pragma unroll
      for (int k = 0; k < 8; k++) {
        *p = (short)(obuf[k >> 1] >> ((k & 1) * 16));
        p += hdelta;
      }
      hflush += 8 * hdelta;
    }
    // next step's gi loads (hide L2/HBM latency under phase A)
    short n0 = 0, n1 = 0, n2 = 0;
    if (s < 511) {
      n0 = gp[0]; n1 = gp[256]; n2 = gp[512];
      gp += gdelta;
    }
    // ---- phase A: gh = h[s] @ w_hh^T (4x conflict-free ds_read_b128) ----
    const char* hs = hb[s & 1];
    i32x4 Af0 = *(const i32x4*)(hs + aof0);
    i32x4 Af1 = *(const i32x4*)(hs + aof1);
    i32x4 Af2 = *(const i32x4*)(hs + aof2);
    i32x4 Af3 = *(const i32x4*)(hs + aof3);
    i32x4 acc0 = zi, acc1 = zi, acc2 = zi;
    acc0 = __builtin_amdgcn_mfma_i32_16x16x64_i8(Af0, Bq[0][0], acc0, 0, 0, 0);
    acc1 = __builtin_amdgcn_mfma_i32_16x16x64_i8(Af0, Bq[1][0], acc1, 0, 0, 0);
    acc2 = __builtin_amdgcn_mfma_i32_16x16x64_i8(Af0, Bq[2][0], acc2, 0, 0, 0);
    acc0 = __builtin_amdgcn_mfma_i32_16x16x64_i8(Af1, Bq[0][1], acc0, 0, 0, 0);
    acc1 = __builtin_amdgcn_mfma_i32_16x16x64_i8(Af1, Bq[1][1], acc1, 0, 0, 0);
    acc2 = __builtin_amdgcn_mfma_i32_16x16x64_i8(Af1, Bq[2][1], acc2, 0, 0, 0);
    acc0 = __builtin_amdgcn_mfma_i32_16x16x64_i8(Af2, Bq[0][2], acc0, 0, 0, 0);
    acc1 = __builtin_amdgcn_mfma_i32_16x16x64_i8(Af2, Bq[1][2], acc1, 0, 0, 0);
    acc2 = __builtin_amdgcn_mfma_i32_16x16x64_i8(Af2, Bq[2][2], acc2, 0, 0, 0);
    acc0 = __builtin_amdgcn_mfma_i32_16x16x64_i8(Af3, Bq[0][3], acc0, 0, 0, 0);
    acc1 = __builtin_amdgcn_mfma_i32_16x16x64_i8(Af3, Bq[1][3], acc1, 0, 0, 0);
    acc2 = __builtin_amdgcn_mfma_i32_16x16x64_i8(Af3, Bq[2][3], acc2, 0, 0, 0);
    // ---- wave-local gate exchange (no barrier; same-wave DS is in-order) ----
    if (quad == 0) {     // C-layout rows 0..3 live in quad 0, col = m15
#pragma unroll
      for (int i = 0; i < 4; i++) {
        smGi[v][i * 16 + m15]       = acc0[i];
        smGi[v][64 + i * 16 + m15]  = acc1[i];
        smGi[v][128 + i * 16 + m15] = acc2[i];
      }
    }
    int igr = smGi[v][lane];          // row=quad, c=m15 -> quad*16+m15 = lane
    int igz = smGi[v][64 + lane];
    int ign = smGi[v][128 + lane];
    // ---- phase B: gates, 1 element/lane ----
    float r = fast_sigmoid(fmaf((float)igr, SCL, gic0 + bh[0]));
    float z = fast_sigmoid(fmaf((float)igz, SCL, gic1 + bh[1]));
    float n = fast_tanh(fmaf(r, fmaf((float)ign, SCL, bh[2]), gic2));
    float h = (1.f - z) * n + z * hprev;
    hprev = h;
    // h -> i8 LDS (swizzled layout) for next step
    int hq = (int)__builtin_rintf(h * 127.f);
    hb[(s + 1) & 1][wofs] = (char)hq;
    // buffer bf16 output (flushed at top of step s+1 when 8 accumulated)
    unsigned hb16 = (unsigned)(unsigned short)f2b(h);
    int idx = s & 7;
    if ((idx & 1) == 0) obuf[idx >> 1] = hb16;
    else                obuf[idx >> 1] |= hb16 << 16;
    gic0 = b2f(n0); gic1 = b2f(n1); gic2 = b2f(n2);
    __syncthreads();   // the one barrier: publishes hb[s+1]
  }
  // final flush (steps 504..511)
  {
    short* p = hflush;
#pragma unroll
    for (int k = 0; k < 8; k++) {
      *p = (short)(obuf[k >> 1] >> ((k & 1) * 16));
      p += hdelta;
    }
  }
}

// ---------------- residual + LayerNorm (ff input bf16) ----------------
// FIRST=1: residual read from bf16 hcat16 (GRU output); else fp32 hres.
template <int FIRST>
__global__ __launch_bounds__(256) void k_ln(const float* __restrict__ hinf,
    const short* __restrict__ ff16, const float* __restrict__ gw,
    const float* __restrict__ bw, float* __restrict__ hout, short* __restrict__ h16) {
  int row = blockIdx.x * 4 + (threadIdx.x >> 6);
  int lane = threadIdx.x & 63;
  size_t base = (size_t)row * 512 + lane * 8;
  f32x4 x0, x1;
  if (FIRST) {
    short8 hv = *(const short8*)(h16 + base);
#pragma unroll
    for (int i = 0; i < 4; i++) { x0[i] = b2f(hv[i]); x1[i] = b2f(hv[4 + i]); }
  } else {
    x0 = *(const f32x4*)(hinf + base);
    x1 = *(const f32x4*)(hinf + base + 4);
  }
  short8 fv = *(const short8*)(ff16 + base);
#pragma unroll
  for (int i = 0; i < 4; i++) { x0[i] += b2f(fv[i]); x1[i] += b2f(fv[4 + i]); }
  float s = x0[0] + x0[1] + x0[2] + x0[3] + x1[0] + x1[1] + x1[2] + x1[3];
#pragma unroll
  for (int off = 32; off >= 1; off >>= 1) s += __shfl_xor(s, off);
  float mu = s * (1.f / 512.f);
  float vv = 0.f;
#pragma unroll
  for (int i = 0; i < 4; i++) { float d0 = x0[i] - mu, d1 = x1[i] - mu; vv += d0 * d0 + d1 * d1; }
#pragma unroll
  for (int off = 32; off >= 1; off >>= 1) vv += __shfl_xor(vv, off);
  float rs = rsqrtf(vv * (1.f / 512.f) + 1e-5f);
  int e = lane * 8;
  f32x4 g0 = *(const f32x4*)(gw + e), g1 = *(const f32x4*)(gw + e + 4);
  f32x4 bb0 = *(const f32x4*)(bw + e), bb1 = *(const f32x4*)(bw + e + 4);
  f32x4 o0, o1; short8 ob;
#pragma unroll
  for (int i = 0; i < 4; i++) {
    float a = (x0[i] - mu) * rs * g0[i] + bb0[i];
    float b = (x1[i] - mu) * rs * g1[i] + bb1[i];
    o0[i] = a; o1[i] = b; ob[i] = f2b(a); ob[4 + i] = f2b(b);
  }
  *(f32x4*)(hout + base) = o0;
  *(f32x4*)(hout + base + 4) = o1;
  *(short8*)(h16 + base) = ob;
}

// ---------------- final FC (N=16), fp32 weights ----------------
__global__ __launch_bounds__(256) void k_fc(const float* __restrict__ h,
    const float* __restrict__ fcw, const float* __restrict__ bias,
    float* __restrict__ logits) {
  int row = blockIdx.x * 4 + (threadIdx.x >> 6);
  int lane = threadIdx.x & 63;
  int c = lane & 15, part = lane >> 4;
  const float* ph = h + (size_t)row * 512 + part * 128;
  const float* pw = fcw + (size_t)part * 128 * 16 + c;
  float acc = 0.f;
#pragma unroll 8
  for (int k = 0; k < 128; k += 4) {
    f32x4 hv = *(const f32x4*)(ph + k);
    acc += hv[0] * pw[(k) * 16] + hv[1] * pw[(k + 1) * 16]
         + hv[2] * pw[(k + 2) * 16] + hv[3] * pw[(k + 3) * 16];
  }
  acc += __shfl_xor(acc, 16);
  acc += __shfl_xor(acc, 32);
  if (part == 0) logits[(size_t)row * 16 + c] = acc + bias[c];
}

// ---------------- CRF Viterbi v2: wave-parallel max-plus ----------------
__global__ __launch_bounds__(64) void k_crf(const float* __restrict__ logits,
    const int* __restrict__ y, const float* __restrict__ trans,
    float* __restrict__ out) {
  __shared__ unsigned char bp[511][16];
  int b = blockIdx.x, lane = threadIdx.x;
  int cur = lane & 15, g = lane >> 4;
  float trr0 = trans[(4 * g + 0) * 16 + cur];
  float trr1 = trans[(4 * g + 1) * 16 + cur];
  float trr2 = trans[(4 * g + 2) * 16 + cur];
  float trr3 = trans[(4 * g + 3) * 16 + cur];
  const float* lg = logits + (size_t)b * 16;
  const int* yb = y + b * 512;
  float score = trans[16 + cur] + lg[cur];    // tr[BOS=1][cur] + emit[0]
  float e_next = lg[512 + cur];
  int y_next = yb[1];
  for (int t = 1; t < 512; t++) {
    float e = e_next; int ym = y_next;
    if (t < 511) { e_next = lg[(t + 1) * 512 + cur]; y_next = yb[t + 1]; }
    float s0 = __shfl(score, 4 * g + 0);
    float s1 = __shfl(score, 4 * g + 1);
    float s2 = __shfl(score, 4 * g + 2);
    float s3 = __shfl(score, 4 * g + 3);
    float best = s0 + trr0; int arg = 4 * g;
    float c1 = s1 + trr1; if (c1 > best) { best = c1; arg = 4 * g + 1; }
    float c2 = s2 + trr2; if (c2 > best) { best = c2; arg = 4 * g + 2; }
    float c3 = s3 + trr3; if (c3 > best) { best = c3; arg = 4 * g + 3; }
    float pv = __shfl_xor(best, 16); int pa = __shfl_xor(arg, 16);
    bool take = (lane & 16) ? (pv >= best) : (pv > best);
    if (take) { best = pv; arg = pa; }
    pv = __shfl_xor(best, 32); pa = __shfl_xor(arg, 32);
    take = (lane & 32) ? (pv >= best) : (pv > best);
    if (take) { best = pv; arg = pa; }
    if (lane < 16) bp[t - 1][cur] = (unsigned char)arg;
    float ns = best + e;
    if (ym == 0) ns = score;
    score = ns;
  }
  score += trans[cur * 16 + 2];               // tr[cur][EOS=2]
  float best = -3.4e38f; int argb = 0;
#pragma unroll
  for (int p = 0; p < 16; p++) {
    float sp = __shfl(score, p);
    if (sp > best) { best = sp; argb = p; }
  }
  __syncthreads();
  if (lane == 0) {
    out[b] = best;
    float* po = out + 32 + (size_t)b * 512;
    int tag = argb;
    po[511] = (float)tag;
    for (int t = 511; t >= 1; t--) {
      int prev = bp[t - 1][tag];
      if (yb[t] == 0) prev = tag;
      po[t - 1] = (float)prev;
      tag = prev;
    }
  }
}

// ---------------- host ----------------
extern "C" void kernel_launch(void* const* d_in, const int* in_sizes, int n_in,
                              void* d_out, int out_size, void* d_ws, size_t ws_size,
                              hipStream_t stream) {
  const int*   x      = (const int*)d_in[0];
  const int*   y      = (const int*)d_in[1];
  const float* embedW = (const float*)d_in[2];
  const float* w_ih_f = (const float*)d_in[3];
  const float* w_hh_f = (const float*)d_in[4];
  const float* b_ih_f = (const float*)d_in[5];
  const float* b_hh_f = (const float*)d_in[6];
  const float* w_ih_b = (const float*)d_in[7];
  const float* w_hh_b = (const float*)d_in[8];
  const float* b_ih_b = (const float*)d_in[9];
  const float* b_hh_b = (const float*)d_in[10];
  const float* ff_w1  = (const float*)d_in[11];
  const float* ff_b1  = (const float*)d_in[12];
  const float* ff_w2  = (const float*)d_in[13];
  const float* ff_b2  = (const float*)d_in[14];
  const float* ln_g   = (const float*)d_in[15];
  const float* ln_b   = (const float*)d_in[16];
  const float* fc_w   = (const float*)d_in[17];
  const float* fc_b   = (const float*)d_in[18];
  const float* trans  = (const float*)d_in[19];
  float* out = (float*)d_out;

  char* ws = (char*)d_ws;
  short* h0     = (short*)(ws + 0);                 // 16.78 MB bf16 (B,T,E)
  short* gi16   = (short*)(ws + 16777216);          // 50.33 MB bf16 [t][b][1536] (f|b)
  short* mid    = (short*)(ws + 16777216);          // 67.1 MB bf16, overlays gi16 (dead after GRU)
  short* ffout16= (short*)(ws + 83886080);          // 16.78 MB bf16 FF output
  short* wihf16 = (short*)(ws + 117440512);         // bf16 (768,512); wihb16 contiguous after
  short* wihb16 = (short*)(ws + 118226944);         //   -> combined (1536,512) B matrix
  int*   wq8    = (int*)  (ws + 119013376);         // i8 frags, 393216 B
  short* w1t    = (short*)(ws + 119799808);         // bf16 (4 x 2048x512)
  short* w2t    = (short*)(ws + 128188416);         // bf16 (4 x 512x2048)
  short* hcat16 = (short*)(ws + 136577024);         // bf16 [t][b][512]
  float* hres   = (float*)(ws + 153354240);         // fp32 residual [t][b][512]
  float* logits = (float*)(ws + 186908672);         // fp32 [t][b][16]

  k_embed<<<4096, 256, 0, stream>>>(x, embedW, h0);
  k_cvt2<<<768, 256, 0, stream>>>(w_ih_f, w_ih_b, wihf16, wihb16);
  k_wq8<<<96, 256, 0, stream>>>(w_hh_f, w_hh_b, wq8);

  // merged ih-projection: A(16384,512) x B(1536,512)^T -> gi16 [t][b][1536]
  k_gemm<3><<<1536, 256, 0, stream>>>(h0, wihf16, b_ih_f, b_ih_b, nullptr, gi16, 16384, 1536, 512);

  // GRU (blocks 0..15) + folded ff_w1/ff_w2 transpose (blocks 16..2063)
  k_gru<<<2064, 1024, 0, stream>>>(wq8, b_hh_f, b_hh_b, gi16, hcat16,
                                   ff_w1, ff_w2, w1t, w2t);

  for (int i = 0; i < 4; i++) {
    k_gemm<1><<<2048, 256, 0, stream>>>(hcat16, w1t + (size_t)i * 1048576, ff_b1 + i * 2048,
                                        nullptr, nullptr, mid, 16384, 2048, 512);
    k_gemm<4><<<512, 256, 0, stream>>>(mid, w2t + (size_t)i * 1048576, ff_b2 + i * 512,
                                       nullptr, nullptr, ffout16, 16384, 512, 2048);
    if (i == 0)
      k_ln<1><<<4096, 256, 0, stream>>>(nullptr, ffout16, ln_g, ln_b, hres, hcat16);
    else
      k_ln<0><<<4096, 256, 0, stream>>>(hres, ffout16, ln_g + i * 512, ln_b + i * 512, hres, hcat16);
  }
  k_fc<<<4096, 256, 0, stream>>>(hres, fc_w, fc_b, logits);
  k_crf<<<32, 64, 0, stream>>>(logits, y, trans, out);
}

// Round 9
// 1504.289 us; speedup vs baseline: 1.0652x; 1.0143x over previous
//
#include <hip/hip_runtime.h>

#define DEV __device__ __forceinline__

using short8 = __attribute__((ext_vector_type(8))) short;
using f32x4  = __attribute__((ext_vector_type(4))) float;
using i32x4  = __attribute__((ext_vector_type(4))) int;

DEV float b2f(short s) {
  union { unsigned u; float f; } c;
  c.u = ((unsigned)(unsigned short)s) << 16;
  return c.f;
}
DEV short f2b(float f) {
  union { float f; unsigned u; } c; c.f = f;
  unsigned u = c.u + 0x7fffu + ((c.u >> 16) & 1u);
  return (short)(u >> 16);
}
DEV float fast_sigmoid(float x) {   // rcp+exp: ~20 cyc vs ~90 for fp32 divide
  return __builtin_amdgcn_rcpf(1.f + __expf(-x));
}
DEV float fast_tanh(float x) {      // 1 - 2/(e^2x+1); saturates correctly at +-inf
  return 1.f - 2.f * __builtin_amdgcn_rcpf(1.f + __expf(2.f * x));
}
// async global->LDS, 16B per lane. LDS dest = uniform base + lane*16.
DEV void async_ld16(const void* g, void* lds) {
  __builtin_amdgcn_global_load_lds(
      (const __attribute__((address_space(1))) void*)(unsigned long long)g,
      (__attribute__((address_space(3))) void*)(unsigned)(unsigned long long)lds,
      16, 0, 0);
}

// ---------------- fp32 -> bf16 convert: w_ih_f, w_ih_b ----------------
__global__ __launch_bounds__(256) void k_cvt2(const float* __restrict__ a, const float* __restrict__ b,
                                              short* __restrict__ oa, short* __restrict__ ob) {
  int blk = blockIdx.x;
  const float* in; short* out; int base;
  if (blk < 384) { in = a; out = oa; base = blk; }
  else           { in = b; out = ob; base = blk - 384; }
  int i = base * 256 + threadIdx.x;
  f32x4 v = *(const f32x4*)(in + (size_t)i * 4);
  short4 o;
#pragma unroll
  for (int j = 0; j < 4; j++) ((short*)&o)[j] = f2b(v[j]);
  *(short4*)(out + (size_t)i * 4) = o;
}

// ---------------- w_hh fp32 -> i8 B-fragments (scale 256) ----------------
// out[d][v(16)][g(3)][c(4)][lane(64)] : 16 bytes = B[n=lane&15][k=c*64+(lane>>4)*16+j]
__global__ __launch_bounds__(256) void k_wq8(const float* __restrict__ wf,
                                             const float* __restrict__ wb,
                                             int* __restrict__ out) {
  int flat = blockIdx.x * 256 + threadIdx.x;   // 24576 total (96 blocks)
  int lane = flat & 63;
  int c = (flat >> 6) & 3;
  int t = flat >> 8;
  int g = t % 3;
  int t2 = t / 3;
  int v = t2 & 15, d = t2 >> 4;
  const float* w = d ? wb : wf;
  int row = g * 256 + v * 16 + (lane & 15);
  int k0 = c * 64 + (lane >> 4) * 16;
  const float* p = w + (size_t)row * 256 + k0;
  int pk[4];
#pragma unroll
  for (int i = 0; i < 4; i++) {
    f32x4 f = *(const f32x4*)(p + i * 4);
    int b0 = (int)__builtin_rintf(f[0] * 256.f);
    int b1 = (int)__builtin_rintf(f[1] * 256.f);
    int b2 = (int)__builtin_rintf(f[2] * 256.f);
    int b3 = (int)__builtin_rintf(f[3] * 256.f);
    b0 = min(127, max(-127, b0)); b1 = min(127, max(-127, b1));
    b2 = min(127, max(-127, b2)); b3 = min(127, max(-127, b3));
    pk[i] = (b0 & 255) | ((b1 & 255) << 8) | ((b2 & 255) << 16) | ((b3 & 255) << 24);
  }
  *(int4*)(out + (size_t)flat * 4) = *(int4*)pk;
}

// ---------------- embed + positional encoding (fp32 W -> bf16 h0) ----------------
__global__ __launch_bounds__(256) void k_embed(const int* __restrict__ x,
                                               const float* __restrict__ W,
                                               short* __restrict__ h0) {
  int flat = blockIdx.x * 256 + threadIdx.x;   // 0 .. 1048575 (B*T*E/8)
  int row  = flat >> 6;                        // b*T + t
  int e0   = (flat & 63) << 3;
  int tok  = x[row];
  int t    = row & 511;
  const float* wp = W + (size_t)tok * 512 + e0;
  float v[8];
  *(f32x4*)v       = *(const f32x4*)(wp);
  *(f32x4*)(v + 4) = *(const f32x4*)(wp + 4);
  short8 o;
#pragma unroll
  for (int i = 0; i < 8; i += 2) {
    float f = expf(-9.210340371976184f * (float)(e0 + i) * (1.f / 512.f));
    float ang = (float)t * f;
    o[i]     = f2b(v[i]     + sinf(ang));
    o[i + 1] = f2b(v[i + 1] + cosf(ang));
  }
  *(short8*)(h0 + (size_t)flat * 8) = o;
}

// ---------------- 128x128 MFMA GEMM, A(M,K) bf16 * B(N,K) bf16 ----------------
// REVERTED to the round-4-measured form (scalar epilogue, unswapped mfma):
// same-config A/B r4-rest=1013 vs r8-rest=1051 showed the swapped-operand
// vectorized epilogue + bf16 ffout package was +38us -- the FF GEMMs are
// main-loop-bound, not epilogue-store-bound. No XCD swizzle (L3-resident).
// MODE 0: fp32 out + bias. MODE 1: bf16 out + bias + relu.
// MODE 3: bf16 out + two biases (cols<768 -> bias, else bias2), written to
//         merged gi16 layout [t][b][1536] (M rows are b*512+t).
template <int MODE>
__global__ __launch_bounds__(256) void k_gemm(const short* __restrict__ A,
    const short* __restrict__ B, const float* __restrict__ bias,
    const float* __restrict__ bias2,
    float* __restrict__ Cf, short* __restrict__ Cb, int M, int N, int K) {
  __shared__ short smA[8192];
  __shared__ short smB[8192];
  const int tid = threadIdx.x, lane = tid & 63, wave = tid >> 6;
  const int m15 = lane & 15, q8 = (lane >> 4) << 3;
  const int tn = N >> 7;
  const int bm = blockIdx.x / tn, bn = blockIdx.x % tn;
  const int wm = wave & 1, wn = wave >> 1;
  const f32x4 z4 = {0.f, 0.f, 0.f, 0.f};
  f32x4 acc[4][4];
#pragma unroll
  for (int i = 0; i < 4; i++)
#pragma unroll
    for (int j = 0; j < 4; j++) acc[i][j] = z4;

  for (int k0 = 0; k0 < K; k0 += 64) {
#pragma unroll
    for (int is = 0; is < 4; is++) {
      int c = is * 4 + wave;
      int mb = c & 7, kb = c >> 3;
      async_ld16(A + (size_t)(bm * 128 + mb * 16 + m15) * K + k0 + kb * 32 + q8, smA + c * 512);
      async_ld16(B + (size_t)(bn * 128 + mb * 16 + m15) * K + k0 + kb * 32 + q8, smB + c * 512);
    }
    __syncthreads();
#pragma unroll
    for (int kk = 0; kk < 2; kk++) {
      short8 af[4], bf[4];
#pragma unroll
      for (int i = 0; i < 4; i++)
        af[i] = *(const short8*)(smA + (kk * 8 + wm * 4 + i) * 512 + lane * 8);
#pragma unroll
      for (int j = 0; j < 4; j++)
        bf[j] = *(const short8*)(smB + (kk * 8 + wn * 4 + j) * 512 + lane * 8);
#pragma unroll
      for (int i = 0; i < 4; i++)
#pragma unroll
        for (int j = 0; j < 4; j++)
          acc[i][j] = __builtin_amdgcn_mfma_f32_16x16x32_bf16(af[i], bf[j], acc[i][j], 0, 0, 0);
    }
    __syncthreads();
  }
#pragma unroll
  for (int j = 0; j < 4; j++) {
    int col = bn * 128 + wn * 64 + j * 16 + m15;
    float bv;
    if (MODE == 3) bv = (col < 768) ? bias[col] : bias2[col - 768];  // block-uniform branch (128|768)
    else           bv = bias[col];
#pragma unroll
    for (int i = 0; i < 4; i++) {
      int row0 = bm * 128 + wm * 64 + i * 16 + ((lane >> 4) << 2);
#pragma unroll
      for (int r = 0; r < 4; r++) {
        float v = acc[i][j][r] + bv;
        int rr = row0 + r;
        if (MODE == 0) {
          Cf[(size_t)rr * N + col] = v;
        } else if (MODE == 1) {
          if (v < 0.f) v = 0.f;
          Cb[(size_t)rr * N + col] = f2b(v);
        } else {
          // merged gi16: [t][b][1536], rr = b*512 + t
          Cb[((size_t)((rr & 511) * 32 + (rr >> 9))) * 1536 + col] = f2b(v);
        }
      }
    }
  }
}

// ---------------- bidirectional GRU v9 + folded FF-weight transpose ----------------
// UNCHANGED from round 8 (measured 475us, fold free in GRU shadow).
// Blocks 0..15: GRU (d = blk&1, bg = blk>>1 -> 4 batch rows), 1024 thr.
// Blocks 16..2063: fp32->bf16 transpose of ff_w1/ff_w2 on the idle 240 CUs.
// GRU phase A: 12 mfma_i32_16x16x64_i8. Gate exchange: smGi wave-local LDS
// (474us r3 vs 510us ds_bpermute r7). The ONLY barrier protects hb.
__global__ __launch_bounds__(1024) void k_gru(
    const int* __restrict__ wq8,
    const float* __restrict__ bhh_f, const float* __restrict__ bhh_b,
    const short* __restrict__ gi16,      // merged [t][b][1536]
    short* __restrict__ hcat16,
    const float* __restrict__ ff_w1, const float* __restrict__ ff_w2,
    short* __restrict__ w1t, short* __restrict__ w2t) {
  __shared__ __align__(16) char smem[20992];   // gru: hb 8192 + smGi 12800; transcvt: 16896
  const int blk = blockIdx.x;
  const int tid = threadIdx.x;

  if (blk >= 16) {
    // ---- transcvt path: 4x (32x32) fp32->bf16 transpose tiles ----
    int sub = tid >> 8, stid = tid & 255;
    int tileid = (blk - 16) * 4 + sub;           // 0..8191
    const float* in; short* out; int C, R, tm;
    if (tileid < 4096) { int mat = tileid >> 10; in = ff_w1 + (size_t)mat * 1048576;
                         out = w1t + (size_t)mat * 1048576; R = 512; C = 2048; tm = tileid & 1023; }
    else               { int mat = (tileid - 4096) >> 10; in = ff_w2 + (size_t)mat * 1048576;
                         out = w2t + (size_t)mat * 1048576; R = 2048; C = 512; tm = tileid & 1023; }
    float (*tile)[33] = (float(*)[33])(smem + sub * 4224);
    int ct = C >> 5;
    int bc = tm % ct, br = tm / ct;
    int r0 = br << 5, c0 = bc << 5;
    for (int i = stid; i < 1024; i += 256) {
      int r = i >> 5, c = i & 31;
      tile[r][c] = in[(size_t)(r0 + r) * C + c0 + c];
    }
    __syncthreads();
    for (int i = stid; i < 1024; i += 256) {
      int c = i >> 5, r = i & 31;
      out[(size_t)(c0 + c) * R + r0 + r] = f2b(tile[r][c]);
    }
    return;
  }

  // ---- GRU path ----
  char (*hb)[4096] = (char(*)[4096])smem;          // i8 h: [row16][256] swizzled, x2
  int (*smGi)[200] = (int(*)[200])(smem + 8192);   // wave-private exchange
  const int d = blk & 1, bg = blk >> 1;
  const int lane = tid & 63, v = tid >> 6;
  const int m15 = lane & 15, quad = lane >> 4;
  const int col = v * 16 + m15;        // this lane's h column
  const int brow = quad;               // this lane's local batch row (0..3)
  const float* bhh = d ? bhh_b : bhh_f;
  const float SCL = 1.f / (127.f * 256.f);

  // B fragments (i8): per-(d,v) stride = 3*4*64 i32x4 entries
  i32x4 Bq[3][4];
  {
    const i32x4* wp = (const i32x4*)wq8 + (size_t)(d * 16 + v) * (3 * 4 * 64);
#pragma unroll
    for (int g = 0; g < 3; g++)
#pragma unroll
      for (int c = 0; c < 4; c++)
        Bq[g][c] = wp[(g * 4 + c) * 64 + lane];
  }
  float bh[3];
#pragma unroll
  for (int g = 0; g < 3; g++) bh[g] = bhh[g * 256 + col];

  // A-read offsets (loop-invariant): 4x b128 per lane, conflict-free
  const int sw = (m15 & 7) << 4;
  const int aof0 = m15 * 256 + ((quad * 16 +   0) ^ sw);
  const int aof1 = m15 * 256 + ((quad * 16 +  64) ^ sw);
  const int aof2 = m15 * 256 + ((quad * 16 + 128) ^ sw);
  const int aof3 = m15 * 256 + ((quad * 16 + 192) ^ sw);
  // h-write offset: row=brow, k=col (linear k layout, chunk-swizzled)
  const int wofs = brow * 256 + (col ^ (brow << 4));

  // zero both h buffers (rows 4..15 stay zero forever)
  for (int i = tid; i < 2048; i += 1024) ((int*)hb)[i] = 0;

  const int t0 = d ? 511 : 0;
  const long gdelta = (long)(d ? -1 : 1) * 32 * 1536;
  const long hdelta = (long)(d ? -1 : 1) * 32 * 512;
  const short* gp = gi16 + ((size_t)t0 * 32 + bg * 4 + brow) * 1536 + d * 768 + col;
  short* hflush = hcat16 + ((size_t)t0 * 32 + bg * 4 + brow) * 512 + d * 256 + col;

  float gic0 = b2f(gp[0]), gic1 = b2f(gp[256]), gic2 = b2f(gp[512]);
  gp += gdelta;
  float hprev = 0.f;
  unsigned obuf[4] = {0u, 0u, 0u, 0u};
  const i32x4 zi = {0, 0, 0, 0};
  __syncthreads();   // hb zero visible

  for (int s = 0; s < 512; s++) {
    // flush previous 8 h outputs at TOP of step: stores drain at this step's
    // end barrier, hidden under phase A instead of serial before it.
    if ((s & 7) == 0 && s) {
      short* p = hflush;
#pragma unroll
      for (int k = 0; k < 8; k++) {
        *p = (short)(obuf[k >> 1] >> ((k & 1) * 16));
        p += hdelta;
      }
      hflush += 8 * hdelta;
    }
    // next step's gi loads (hide L2/HBM latency under phase A)
    short n0 = 0, n1 = 0, n2 = 0;
    if (s < 511) {
      n0 = gp[0]; n1 = gp[256]; n2 = gp[512];
      gp += gdelta;
    }
    // ---- phase A: gh = h[s] @ w_hh^T (4x conflict-free ds_read_b128) ----
    const char* hs = hb[s & 1];
    i32x4 Af0 = *(const i32x4*)(hs + aof0);
    i32x4 Af1 = *(const i32x4*)(hs + aof1);
    i32x4 Af2 = *(const i32x4*)(hs + aof2);
    i32x4 Af3 = *(const i32x4*)(hs + aof3);
    i32x4 acc0 = zi, acc1 = zi, acc2 = zi;
    acc0 = __builtin_amdgcn_mfma_i32_16x16x64_i8(Af0, Bq[0][0], acc0, 0, 0, 0);
    acc1 = __builtin_amdgcn_mfma_i32_16x16x64_i8(Af0, Bq[1][0], acc1, 0, 0, 0);
    acc2 = __builtin_amdgcn_mfma_i32_16x16x64_i8(Af0, Bq[2][0], acc2, 0, 0, 0);
    acc0 = __builtin_amdgcn_mfma_i32_16x16x64_i8(Af1, Bq[0][1], acc0, 0, 0, 0);
    acc1 = __builtin_amdgcn_mfma_i32_16x16x64_i8(Af1, Bq[1][1], acc1, 0, 0, 0);
    acc2 = __builtin_amdgcn_mfma_i32_16x16x64_i8(Af1, Bq[2][1], acc2, 0, 0, 0);
    acc0 = __builtin_amdgcn_mfma_i32_16x16x64_i8(Af2, Bq[0][2], acc0, 0, 0, 0);
    acc1 = __builtin_amdgcn_mfma_i32_16x16x64_i8(Af2, Bq[1][2], acc1, 0, 0, 0);
    acc2 = __builtin_amdgcn_mfma_i32_16x16x64_i8(Af2, Bq[2][2], acc2, 0, 0, 0);
    acc0 = __builtin_amdgcn_mfma_i32_16x16x64_i8(Af3, Bq[0][3], acc0, 0, 0, 0);
    acc1 = __builtin_amdgcn_mfma_i32_16x16x64_i8(Af3, Bq[1][3], acc1, 0, 0, 0);
    acc2 = __builtin_amdgcn_mfma_i32_16x16x64_i8(Af3, Bq[2][3], acc2, 0, 0, 0);
    // ---- wave-local gate exchange (no barrier; same-wave DS is in-order) ----
    if (quad == 0) {     // C-layout rows 0..3 live in quad 0, col = m15
#pragma unroll
      for (int i = 0; i < 4; i++) {
        smGi[v][i * 16 + m15]       = acc0[i];
        smGi[v][64 + i * 16 + m15]  = acc1[i];
        smGi[v][128 + i * 16 + m15] = acc2[i];
      }
    }
    int igr = smGi[v][lane];          // row=quad, c=m15 -> quad*16+m15 = lane
    int igz = smGi[v][64 + lane];
    int ign = smGi[v][128 + lane];
    // ---- phase B: gates, 1 element/lane ----
    float r = fast_sigmoid(fmaf((float)igr, SCL, gic0 + bh[0]));
    float z = fast_sigmoid(fmaf((float)igz, SCL, gic1 + bh[1]));
    float n = fast_tanh(fmaf(r, fmaf((float)ign, SCL, bh[2]), gic2));
    float h = (1.f - z) * n + z * hprev;
    hprev = h;
    // h -> i8 LDS (swizzled layout) for next step
    int hq = (int)__builtin_rintf(h * 127.f);
    hb[(s + 1) & 1][wofs] = (char)hq;
    // buffer bf16 output (flushed at top of step s+1 when 8 accumulated)
    unsigned hb16 = (unsigned)(unsigned short)f2b(h);
    int idx = s & 7;
    if ((idx & 1) == 0) obuf[idx >> 1] = hb16;
    else                obuf[idx >> 1] |= hb16 << 16;
    gic0 = b2f(n0); gic1 = b2f(n1); gic2 = b2f(n2);
    __syncthreads();   // the one barrier: publishes hb[s+1]
  }
  // final flush (steps 504..511)
  {
    short* p = hflush;
#pragma unroll
    for (int k = 0; k < 8; k++) {
      *p = (short)(obuf[k >> 1] >> ((k & 1) * 16));
      p += hdelta;
    }
  }
}

// ---------------- residual + LayerNorm (round-4 form: fp32 ff input) ----------------
// FIRST=1: residual read from bf16 hcat16 (GRU output); else fp32 hres.
template <int FIRST>
__global__ __launch_bounds__(256) void k_ln(const float* __restrict__ hinf,
    const float* __restrict__ ff, const float* __restrict__ gw,
    const float* __restrict__ bw, float* __restrict__ hout, short* __restrict__ h16) {
  int row = blockIdx.x * 4 + (threadIdx.x >> 6);
  int lane = threadIdx.x & 63;
  size_t base = (size_t)row * 512 + lane * 8;
  f32x4 x0, x1;
  if (FIRST) {
    short8 hv = *(const short8*)(h16 + base);
#pragma unroll
    for (int i = 0; i < 4; i++) { x0[i] = b2f(hv[i]); x1[i] = b2f(hv[4 + i]); }
  } else {
    x0 = *(const f32x4*)(hinf + base);
    x1 = *(const f32x4*)(hinf + base + 4);
  }
  f32x4 y0 = *(const f32x4*)(ff + base);
  f32x4 y1 = *(const f32x4*)(ff + base + 4);
  x0 += y0; x1 += y1;
  float s = x0[0] + x0[1] + x0[2] + x0[3] + x1[0] + x1[1] + x1[2] + x1[3];
#pragma unroll
  for (int off = 32; off >= 1; off >>= 1) s += __shfl_xor(s, off);
  float mu = s * (1.f / 512.f);
  float vv = 0.f;
#pragma unroll
  for (int i = 0; i < 4; i++) { float d0 = x0[i] - mu, d1 = x1[i] - mu; vv += d0 * d0 + d1 * d1; }
#pragma unroll
  for (int off = 32; off >= 1; off >>= 1) vv += __shfl_xor(vv, off);
  float rs = rsqrtf(vv * (1.f / 512.f) + 1e-5f);
  int e = lane * 8;
  f32x4 g0 = *(const f32x4*)(gw + e), g1 = *(const f32x4*)(gw + e + 4);
  f32x4 bb0 = *(const f32x4*)(bw + e), bb1 = *(const f32x4*)(bw + e + 4);
  f32x4 o0, o1; short8 ob;
#pragma unroll
  for (int i = 0; i < 4; i++) {
    float a = (x0[i] - mu) * rs * g0[i] + bb0[i];
    float b = (x1[i] - mu) * rs * g1[i] + bb1[i];
    o0[i] = a; o1[i] = b; ob[i] = f2b(a); ob[4 + i] = f2b(b);
  }
  *(f32x4*)(hout + base) = o0;
  *(f32x4*)(hout + base + 4) = o1;
  *(short8*)(h16 + base) = ob;
}

// ---------------- final FC (N=16), fp32 weights ----------------
__global__ __launch_bounds__(256) void k_fc(const float* __restrict__ h,
    const float* __restrict__ fcw, const float* __restrict__ bias,
    float* __restrict__ logits) {
  int row = blockIdx.x * 4 + (threadIdx.x >> 6);
  int lane = threadIdx.x & 63;
  int c = lane & 15, part = lane >> 4;
  const float* ph = h + (size_t)row * 512 + part * 128;
  const float* pw = fcw + (size_t)part * 128 * 16 + c;
  float acc = 0.f;
#pragma unroll 8
  for (int k = 0; k < 128; k += 4) {
    f32x4 hv = *(const f32x4*)(ph + k);
    acc += hv[0] * pw[(k) * 16] + hv[1] * pw[(k + 1) * 16]
         + hv[2] * pw[(k + 2) * 16] + hv[3] * pw[(k + 3) * 16];
  }
  acc += __shfl_xor(acc, 16);
  acc += __shfl_xor(acc, 32);
  if (part == 0) logits[(size_t)row * 16 + c] = acc + bias[c];
}

// ---------------- CRF Viterbi v3: LDS-staged emissions ----------------
// v2's main loop exposed one L2 global load per step (1-step prefetch < L2
// latency). v3 stages the whole per-b emission table (512x16 f32 = 32 KB) and
// y-mask (2 KB) into LDS up front (coalesced f32x4 stream, independent loads),
// then the 512-step recurrence runs entirely on registers + LDS broadcasts
// (16 addresses over 16 banks, 4-way broadcast = conflict-free). Backtrack is
// LDS-only too. Max-plus math identical to v2 (passed r4/r7/r8).
__global__ __launch_bounds__(64) void k_crf(const float* __restrict__ logits,
    const int* __restrict__ y, const float* __restrict__ trans,
    float* __restrict__ out) {
  __shared__ float elds[512][16];          // 32 KB
  __shared__ int   yds[512];               // 2 KB
  __shared__ unsigned char bp[511][16];    // ~8 KB
  int b = blockIdx.x, lane = threadIdx.x;
  int cur = lane & 15, g = lane >> 4;
  // stage emissions: element (t,c) at logits[t*512 + b*16 + c]
  {
    const float* lg = logits + (size_t)b * 16;
    int t0 = lane >> 2, c4 = (lane & 3) * 4;
#pragma unroll 4
    for (int it = 0; it < 32; it++) {
      int t = t0 + it * 16;
      *(f32x4*)&elds[t][c4] = *(const f32x4*)(lg + (size_t)t * 512 + c4);
    }
    const int* yb = y + b * 512;
    for (int i = lane; i < 512; i += 64) yds[i] = yb[i];
  }
  float trr0 = trans[(4 * g + 0) * 16 + cur];
  float trr1 = trans[(4 * g + 1) * 16 + cur];
  float trr2 = trans[(4 * g + 2) * 16 + cur];
  float trr3 = trans[(4 * g + 3) * 16 + cur];
  __syncthreads();   // staging visible (single wave: also in-order, belt+braces)
  float score = trans[16 + cur] + elds[0][cur];    // tr[BOS=1][cur] + emit[0]
  for (int t = 1; t < 512; t++) {
    float s0 = __shfl(score, 4 * g + 0);
    float s1 = __shfl(score, 4 * g + 1);
    float s2 = __shfl(score, 4 * g + 2);
    float s3 = __shfl(score, 4 * g + 3);
    float best = s0 + trr0; int arg = 4 * g;
    float c1 = s1 + trr1; if (c1 > best) { best = c1; arg = 4 * g + 1; }
    float c2 = s2 + trr2; if (c2 > best) { best = c2; arg = 4 * g + 2; }
    float c3 = s3 + trr3; if (c3 > best) { best = c3; arg = 4 * g + 3; }
    // merge across g-pairs; lower-p side wins ties (matches ascending scan)
    float pv = __shfl_xor(best, 16); int pa = __shfl_xor(arg, 16);
    bool take = (lane & 16) ? (pv >= best) : (pv > best);
    if (take) { best = pv; arg = pa; }
    pv = __shfl_xor(best, 32); pa = __shfl_xor(arg, 32);
    take = (lane & 32) ? (pv >= best) : (pv > best);
    if (take) { best = pv; arg = pa; }
    if (lane < 16) bp[t - 1][cur] = (unsigned char)arg;
    float ns = best + elds[t][cur];
    if (yds[t] == 0) ns = score;
    score = ns;
  }
  score += trans[cur * 16 + 2];               // tr[cur][EOS=2]
  float best = -3.4e38f; int argb = 0;
#pragma unroll
  for (int p = 0; p < 16; p++) {
    float sp = __shfl(score, p);
    if (sp > best) { best = sp; argb = p; }
  }
  __syncthreads();
  if (lane == 0) {
    out[b] = best;
    float* po = out + 32 + (size_t)b * 512;
    int tag = argb;
    po[511] = (float)tag;
    for (int t = 511; t >= 1; t--) {
      int prev = bp[t - 1][tag];
      if (yds[t] == 0) prev = tag;
      po[t - 1] = (float)prev;
      tag = prev;
    }
  }
}

// ---------------- host ----------------
extern "C" void kernel_launch(void* const* d_in, const int* in_sizes, int n_in,
                              void* d_out, int out_size, void* d_ws, size_t ws_size,
                              hipStream_t stream) {
  const int*   x      = (const int*)d_in[0];
  const int*   y      = (const int*)d_in[1];
  const float* embedW = (const float*)d_in[2];
  const float* w_ih_f = (const float*)d_in[3];
  const float* w_hh_f = (const float*)d_in[4];
  const float* b_ih_f = (const float*)d_in[5];
  const float* b_hh_f = (const float*)d_in[6];
  const float* w_ih_b = (const float*)d_in[7];
  const float* w_hh_b = (const float*)d_in[8];
  const float* b_ih_b = (const float*)d_in[9];
  const float* b_hh_b = (const float*)d_in[10];
  const float* ff_w1  = (const float*)d_in[11];
  const float* ff_b1  = (const float*)d_in[12];
  const float* ff_w2  = (const float*)d_in[13];
  const float* ff_b2  = (const float*)d_in[14];
  const float* ln_g   = (const float*)d_in[15];
  const float* ln_b   = (const float*)d_in[16];
  const float* fc_w   = (const float*)d_in[17];
  const float* fc_b   = (const float*)d_in[18];
  const float* trans  = (const float*)d_in[19];
  float* out = (float*)d_out;

  char* ws = (char*)d_ws;
  short* h0     = (short*)(ws + 0);                 // 16.78 MB bf16 (B,T,E)
  short* gi16   = (short*)(ws + 16777216);          // 50.33 MB bf16 [t][b][1536] (f|b)
  short* mid    = (short*)(ws + 16777216);          // 67.1 MB bf16, overlays gi16 (dead after GRU)
  float* ffout  = (float*)(ws + 83886080);          // 33.55 MB fp32 FF output
  short* wihf16 = (short*)(ws + 117440512);         // bf16 (768,512); wihb16 contiguous after
  short* wihb16 = (short*)(ws + 118226944);         //   -> combined (1536,512) B matrix
  int*   wq8    = (int*)  (ws + 119013376);         // i8 frags, 393216 B
  short* w1t    = (short*)(ws + 119799808);         // bf16 (4 x 2048x512)
  short* w2t    = (short*)(ws + 128188416);         // bf16 (4 x 512x2048)
  short* hcat16 = (short*)(ws + 136577024);         // bf16 [t][b][512]
  float* hres   = (float*)(ws + 153354240);         // fp32 residual [t][b][512]
  float* logits = (float*)(ws + 186908672);         // fp32 [t][b][16]

  k_embed<<<4096, 256, 0, stream>>>(x, embedW, h0);
  k_cvt2<<<768, 256, 0, stream>>>(w_ih_f, w_ih_b, wihf16, wihb16);
  k_wq8<<<96, 256, 0, stream>>>(w_hh_f, w_hh_b, wq8);

  // merged ih-projection: A(16384,512) x B(1536,512)^T -> gi16 [t][b][1536]
  k_gemm<3><<<1536, 256, 0, stream>>>(h0, wihf16, b_ih_f, b_ih_b, nullptr, gi16, 16384, 1536, 512);

  // GRU (blocks 0..15) + folded ff_w1/ff_w2 transpose (blocks 16..2063)
  k_gru<<<2064, 1024, 0, stream>>>(wq8, b_hh_f, b_hh_b, gi16, hcat16,
                                   ff_w1, ff_w2, w1t, w2t);

  for (int i = 0; i < 4; i++) {
    k_gemm<1><<<2048, 256, 0, stream>>>(hcat16, w1t + (size_t)i * 1048576, ff_b1 + i * 2048,
                                        nullptr, nullptr, mid, 16384, 2048, 512);
    k_gemm<0><<<512, 256, 0, stream>>>(mid, w2t + (size_t)i * 1048576, ff_b2 + i * 512,
                                       nullptr, ffout, nullptr, 16384, 512, 2048);
    if (i == 0)
      k_ln<1><<<4096, 256, 0, stream>>>(nullptr, ffout, ln_g, ln_b, hres, hcat16);
    else
      k_ln<0><<<4096, 256, 0, stream>>>(hres, ffout, ln_g + i * 512, ln_b + i * 512, hres, hcat16);
  }
  k_fc<<<4096, 256, 0, stream>>>(hres, fc_w, fc_b, logits);
  k_crf<<<32, 64, 0, stream>>>(logits, y, trans, out);
}

// Round 10
// 1493.913 us; speedup vs baseline: 1.0726x; 1.0069x over previous
//
#include <hip/hip_runtime.h>

#define DEV __device__ __forceinline__

using short8 = __attribute__((ext_vector_type(8))) short;
using f32x4  = __attribute__((ext_vector_type(4))) float;
using i32x4  = __attribute__((ext_vector_type(4))) int;

DEV float b2f(short s) {
  union { unsigned u; float f; } c;
  c.u = ((unsigned)(unsigned short)s) << 16;
  return c.f;
}
DEV short f2b(float f) {
  union { float f; unsigned u; } c; c.f = f;
  unsigned u = c.u + 0x7fffu + ((c.u >> 16) & 1u);
  return (short)(u >> 16);
}
DEV float fast_sigmoid(float x) {   // rcp+exp: ~20 cyc vs ~90 for fp32 divide
  return __builtin_amdgcn_rcpf(1.f + __expf(-x));
}
DEV float fast_tanh(float x) {      // 1 - 2/(e^2x+1); saturates correctly at +-inf
  return 1.f - 2.f * __builtin_amdgcn_rcpf(1.f + __expf(2.f * x));
}
// async global->LDS, 16B per lane. LDS dest = uniform base + lane*16.
DEV void async_ld16(const void* g, void* lds) {
  __builtin_amdgcn_global_load_lds(
      (const __attribute__((address_space(1))) void*)(unsigned long long)g,
      (__attribute__((address_space(3))) void*)(unsigned)(unsigned long long)lds,
      16, 0, 0);
}

// ---------------- positional-encoding table: pe[t][e], 512x512 fp32 ----------------
// Moves 8.4M threads' worth of expf/sinf/cosf (VALU/transcendental-bound,
// Common-mistake: on-device trig in a memory-bound op) into a 3us one-shot
// 131072-thread kernel. Same expressions/op-order as the old k_embed ->
// bit-identical h0.
__global__ __launch_bounds__(256) void k_pe(float* __restrict__ pe) {
  int flat = blockIdx.x * 256 + threadIdx.x;   // 0..131071
  int t = flat >> 8, p = flat & 255;
  int e = p * 2;
  float f = expf(-9.210340371976184f * (float)e * (1.f / 512.f));
  float ang = (float)t * f;
  float2 v = make_float2(sinf(ang), cosf(ang));
  *(float2*)(pe + (size_t)t * 512 + e) = v;
}

// ---------------- fp32 -> bf16 convert: w_ih_f, w_ih_b ----------------
__global__ __launch_bounds__(256) void k_cvt2(const float* __restrict__ a, const float* __restrict__ b,
                                              short* __restrict__ oa, short* __restrict__ ob) {
  int blk = blockIdx.x;
  const float* in; short* out; int base;
  if (blk < 384) { in = a; out = oa; base = blk; }
  else           { in = b; out = ob; base = blk - 384; }
  int i = base * 256 + threadIdx.x;
  f32x4 v = *(const f32x4*)(in + (size_t)i * 4);
  short4 o;
#pragma unroll
  for (int j = 0; j < 4; j++) ((short*)&o)[j] = f2b(v[j]);
  *(short4*)(out + (size_t)i * 4) = o;
}

// ---------------- w_hh fp32 -> i8 B-fragments (scale 256) ----------------
// out[d][v(16)][g(3)][c(4)][lane(64)] : 16 bytes = B[n=lane&15][k=c*64+(lane>>4)*16+j]
__global__ __launch_bounds__(256) void k_wq8(const float* __restrict__ wf,
                                             const float* __restrict__ wb,
                                             int* __restrict__ out) {
  int flat = blockIdx.x * 256 + threadIdx.x;   // 24576 total (96 blocks)
  int lane = flat & 63;
  int c = (flat >> 6) & 3;
  int t = flat >> 8;
  int g = t % 3;
  int t2 = t / 3;
  int v = t2 & 15, d = t2 >> 4;
  const float* w = d ? wb : wf;
  int row = g * 256 + v * 16 + (lane & 15);
  int k0 = c * 64 + (lane >> 4) * 16;
  const float* p = w + (size_t)row * 256 + k0;
  int pk[4];
#pragma unroll
  for (int i = 0; i < 4; i++) {
    f32x4 f = *(const f32x4*)(p + i * 4);
    int b0 = (int)__builtin_rintf(f[0] * 256.f);
    int b1 = (int)__builtin_rintf(f[1] * 256.f);
    int b2 = (int)__builtin_rintf(f[2] * 256.f);
    int b3 = (int)__builtin_rintf(f[3] * 256.f);
    b0 = min(127, max(-127, b0)); b1 = min(127, max(-127, b1));
    b2 = min(127, max(-127, b2)); b3 = min(127, max(-127, b3));
    pk[i] = (b0 & 255) | ((b1 & 255) << 8) | ((b2 & 255) << 16) | ((b3 & 255) << 24);
  }
  *(int4*)(out + (size_t)flat * 4) = *(int4*)pk;
}

// ---------------- embed + PE-table add (fp32 W -> bf16 h0), pure streaming ----------------
__global__ __launch_bounds__(256) void k_embed(const int* __restrict__ x,
                                               const float* __restrict__ W,
                                               const float* __restrict__ pe,
                                               short* __restrict__ h0) {
  int flat = blockIdx.x * 256 + threadIdx.x;   // 0 .. 1048575 (B*T*E/8)
  int row  = flat >> 6;                        // b*T + t
  int e0   = (flat & 63) << 3;
  int tok  = x[row];
  int t    = row & 511;
  const float* wp = W + (size_t)tok * 512 + e0;
  const float* pp = pe + (size_t)t * 512 + e0;
  f32x4 a0 = *(const f32x4*)(wp);
  f32x4 a1 = *(const f32x4*)(wp + 4);
  f32x4 p0 = *(const f32x4*)(pp);
  f32x4 p1 = *(const f32x4*)(pp + 4);
  short8 o;
#pragma unroll
  for (int i = 0; i < 4; i++) {
    o[i]     = f2b(a0[i] + p0[i]);
    o[4 + i] = f2b(a1[i] + p1[i]);
  }
  *(short8*)(h0 + (size_t)flat * 8) = o;
}

// ---------------- 128x128 MFMA GEMM, A(M,K) bf16 * B(N,K) bf16 ----------------
// Round-4-measured form (scalar epilogue, unswapped mfma): same-config A/B
// r4-rest=1013 vs r8-rest=1051 showed the swapped-operand vectorized epilogue
// package was a regression -- FF GEMMs are main-loop-bound. No XCD swizzle
// (L3-resident working sets).
// MODE 0: fp32 out + bias. MODE 1: bf16 out + bias + relu.
// MODE 4: bf16 out + bias (no relu) -- halves gemm<0> write traffic + LN read.
// MODE 3: bf16 out + two biases (cols<768 -> bias, else bias2), written to
//         merged gi16 layout [t][b][1536] (M rows are b*512+t).
template <int MODE>
__global__ __launch_bounds__(256) void k_gemm(const short* __restrict__ A,
    const short* __restrict__ B, const float* __restrict__ bias,
    const float* __restrict__ bias2,
    float* __restrict__ Cf, short* __restrict__ Cb, int M, int N, int K) {
  __shared__ short smA[8192];
  __shared__ short smB[8192];
  const int tid = threadIdx.x, lane = tid & 63, wave = tid >> 6;
  const int m15 = lane & 15, q8 = (lane >> 4) << 3;
  const int tn = N >> 7;
  const int bm = blockIdx.x / tn, bn = blockIdx.x % tn;
  const int wm = wave & 1, wn = wave >> 1;
  const f32x4 z4 = {0.f, 0.f, 0.f, 0.f};
  f32x4 acc[4][4];
#pragma unroll
  for (int i = 0; i < 4; i++)
#pragma unroll
    for (int j = 0; j < 4; j++) acc[i][j] = z4;

  for (int k0 = 0; k0 < K; k0 += 64) {
#pragma unroll
    for (int is = 0; is < 4; is++) {
      int c = is * 4 + wave;
      int mb = c & 7, kb = c >> 3;
      async_ld16(A + (size_t)(bm * 128 + mb * 16 + m15) * K + k0 + kb * 32 + q8, smA + c * 512);
      async_ld16(B + (size_t)(bn * 128 + mb * 16 + m15) * K + k0 + kb * 32 + q8, smB + c * 512);
    }
    __syncthreads();
#pragma unroll
    for (int kk = 0; kk < 2; kk++) {
      short8 af[4], bf[4];
#pragma unroll
      for (int i = 0; i < 4; i++)
        af[i] = *(const short8*)(smA + (kk * 8 + wm * 4 + i) * 512 + lane * 8);
#pragma unroll
      for (int j = 0; j < 4; j++)
        bf[j] = *(const short8*)(smB + (kk * 8 + wn * 4 + j) * 512 + lane * 8);
#pragma unroll
      for (int i = 0; i < 4; i++)
#pragma unroll
        for (int j = 0; j < 4; j++)
          acc[i][j] = __builtin_amdgcn_mfma_f32_16x16x32_bf16(af[i], bf[j], acc[i][j], 0, 0, 0);
    }
    __syncthreads();
  }
#pragma unroll
  for (int j = 0; j < 4; j++) {
    int col = bn * 128 + wn * 64 + j * 16 + m15;
    float bv;
    if (MODE == 3) bv = (col < 768) ? bias[col] : bias2[col - 768];  // block-uniform branch (128|768)
    else           bv = bias[col];
#pragma unroll
    for (int i = 0; i < 4; i++) {
      int row0 = bm * 128 + wm * 64 + i * 16 + ((lane >> 4) << 2);
#pragma unroll
      for (int r = 0; r < 4; r++) {
        float v = acc[i][j][r] + bv;
        int rr = row0 + r;
        if (MODE == 0) {
          Cf[(size_t)rr * N + col] = v;
        } else if (MODE == 1) {
          if (v < 0.f) v = 0.f;
          Cb[(size_t)rr * N + col] = f2b(v);
        } else if (MODE == 4) {
          Cb[(size_t)rr * N + col] = f2b(v);
        } else {
          // merged gi16: [t][b][1536], rr = b*512 + t
          Cb[((size_t)((rr & 511) * 32 + (rr >> 9))) * 1536 + col] = f2b(v);
        }
      }
    }
  }
}

// ---------------- bidirectional GRU v9 + folded FF-weight transpose ----------------
// UNCHANGED (measured 475-478us across r8/r9; fold free in GRU shadow).
// Blocks 0..15: GRU (d = blk&1, bg = blk>>1 -> 4 batch rows), 1024 thr.
// Blocks 16..2063: fp32->bf16 transpose of ff_w1/ff_w2 on the idle 240 CUs.
// GRU phase A: 12 mfma_i32_16x16x64_i8. Gate exchange: smGi wave-local LDS
// (474us r3 vs 510us ds_bpermute r7). The ONLY barrier protects hb.
__global__ __launch_bounds__(1024) void k_gru(
    const int* __restrict__ wq8,
    const float* __restrict__ bhh_f, const float* __restrict__ bhh_b,
    const short* __restrict__ gi16,      // merged [t][b][1536]
    short* __restrict__ hcat16,
    const float* __restrict__ ff_w1, const float* __restrict__ ff_w2,
    short* __restrict__ w1t, short* __restrict__ w2t) {
  __shared__ __align__(16) char smem[20992];   // gru: hb 8192 + smGi 12800; transcvt: 16896
  const int blk = blockIdx.x;
  const int tid = threadIdx.x;

  if (blk >= 16) {
    // ---- transcvt path: 4x (32x32) fp32->bf16 transpose tiles ----
    int sub = tid >> 8, stid = tid & 255;
    int tileid = (blk - 16) * 4 + sub;           // 0..8191
    const float* in; short* out; int C, R, tm;
    if (tileid < 4096) { int mat = tileid >> 10; in = ff_w1 + (size_t)mat * 1048576;
                         out = w1t + (size_t)mat * 1048576; R = 512; C = 2048; tm = tileid & 1023; }
    else               { int mat = (tileid - 4096) >> 10; in = ff_w2 + (size_t)mat * 1048576;
                         out = w2t + (size_t)mat * 1048576; R = 2048; C = 512; tm = tileid & 1023; }
    float (*tile)[33] = (float(*)[33])(smem + sub * 4224);
    int ct = C >> 5;
    int bc = tm % ct, br = tm / ct;
    int r0 = br << 5, c0 = bc << 5;
    for (int i = stid; i < 1024; i += 256) {
      int r = i >> 5, c = i & 31;
      tile[r][c] = in[(size_t)(r0 + r) * C + c0 + c];
    }
    __syncthreads();
    for (int i = stid; i < 1024; i += 256) {
      int c = i >> 5, r = i & 31;
      out[(size_t)(c0 + c) * R + r0 + r] = f2b(tile[r][c]);
    }
    return;
  }

  // ---- GRU path ----
  char (*hb)[4096] = (char(*)[4096])smem;          // i8 h: [row16][256] swizzled, x2
  int (*smGi)[200] = (int(*)[200])(smem + 8192);   // wave-private exchange
  const int d = blk & 1, bg = blk >> 1;
  const int lane = tid & 63, v = tid >> 6;
  const int m15 = lane & 15, quad = lane >> 4;
  const int col = v * 16 + m15;        // this lane's h column
  const int brow = quad;               // this lane's local batch row (0..3)
  const float* bhh = d ? bhh_b : bhh_f;
  const float SCL = 1.f / (127.f * 256.f);

  // B fragments (i8): per-(d,v) stride = 3*4*64 i32x4 entries
  i32x4 Bq[3][4];
  {
    const i32x4* wp = (const i32x4*)wq8 + (size_t)(d * 16 + v) * (3 * 4 * 64);
#pragma unroll
    for (int g = 0; g < 3; g++)
#pragma unroll
      for (int c = 0; c < 4; c++)
        Bq[g][c] = wp[(g * 4 + c) * 64 + lane];
  }
  float bh[3];
#pragma unroll
  for (int g = 0; g < 3; g++) bh[g] = bhh[g * 256 + col];

  // A-read offsets (loop-invariant): 4x b128 per lane, conflict-free
  const int sw = (m15 & 7) << 4;
  const int aof0 = m15 * 256 + ((quad * 16 +   0) ^ sw);
  const int aof1 = m15 * 256 + ((quad * 16 +  64) ^ sw);
  const int aof2 = m15 * 256 + ((quad * 16 + 128) ^ sw);
  const int aof3 = m15 * 256 + ((quad * 16 + 192) ^ sw);
  // h-write offset: row=brow, k=col (linear k layout, chunk-swizzled)
  const int wofs = brow * 256 + (col ^ (brow << 4));

  // zero both h buffers (rows 4..15 stay zero forever)
  for (int i = tid; i < 2048; i += 1024) ((int*)hb)[i] = 0;

  const int t0 = d ? 511 : 0;
  const long gdelta = (long)(d ? -1 : 1) * 32 * 1536;
  const long hdelta = (long)(d ? -1 : 1) * 32 * 512;
  const short* gp = gi16 + ((size_t)t0 * 32 + bg * 4 + brow) * 1536 + d * 768 + col;
  short* hflush = hcat16 + ((size_t)t0 * 32 + bg * 4 + brow) * 512 + d * 256 + col;

  float gic0 = b2f(gp[0]), gic1 = b2f(gp[256]), gic2 = b2f(gp[512]);
  gp += gdelta;
  float hprev = 0.f;
  unsigned obuf[4] = {0u, 0u, 0u, 0u};
  const i32x4 zi = {0, 0, 0, 0};
  __syncthreads();   // hb zero visible

  for (int s = 0; s < 512; s++) {
    // flush previous 8 h outputs at TOP of step: stores drain at this step's
    // end barrier, hidden under phase A instead of serial before it.
    if ((s & 7) == 0 && s) {
      short* p = hflush;
#pragma unroll
      for (int k = 0; k < 8; k++) {
        *p = (short)(obuf[k >> 1] >> ((k & 1) * 16));
        p += hdelta;
      }
      hflush += 8 * hdelta;
    }
    // next step's gi loads (hide L2/HBM latency under phase A)
    short n0 = 0, n1 = 0, n2 = 0;
    if (s < 511) {
      n0 = gp[0]; n1 = gp[256]; n2 = gp[512];
      gp += gdelta;
    }
    // ---- phase A: gh = h[s] @ w_hh^T (4x conflict-free ds_read_b128) ----
    const char* hs = hb[s & 1];
    i32x4 Af0 = *(const i32x4*)(hs + aof0);
    i32x4 Af1 = *(const i32x4*)(hs + aof1);
    i32x4 Af2 = *(const i32x4*)(hs + aof2);
    i32x4 Af3 = *(const i32x4*)(hs + aof3);
    i32x4 acc0 = zi, acc1 = zi, acc2 = zi;
    acc0 = __builtin_amdgcn_mfma_i32_16x16x64_i8(Af0, Bq[0][0], acc0, 0, 0, 0);
    acc1 = __builtin_amdgcn_mfma_i32_16x16x64_i8(Af0, Bq[1][0], acc1, 0, 0, 0);
    acc2 = __builtin_amdgcn_mfma_i32_16x16x64_i8(Af0, Bq[2][0], acc2, 0, 0, 0);
    acc0 = __builtin_amdgcn_mfma_i32_16x16x64_i8(Af1, Bq[0][1], acc0, 0, 0, 0);
    acc1 = __builtin_amdgcn_mfma_i32_16x16x64_i8(Af1, Bq[1][1], acc1, 0, 0, 0);
    acc2 = __builtin_amdgcn_mfma_i32_16x16x64_i8(Af1, Bq[2][1], acc2, 0, 0, 0);
    acc0 = __builtin_amdgcn_mfma_i32_16x16x64_i8(Af2, Bq[0][2], acc0, 0, 0, 0);
    acc1 = __builtin_amdgcn_mfma_i32_16x16x64_i8(Af2, Bq[1][2], acc1, 0, 0, 0);
    acc2 = __builtin_amdgcn_mfma_i32_16x16x64_i8(Af2, Bq[2][2], acc2, 0, 0, 0);
    acc0 = __builtin_amdgcn_mfma_i32_16x16x64_i8(Af3, Bq[0][3], acc0, 0, 0, 0);
    acc1 = __builtin_amdgcn_mfma_i32_16x16x64_i8(Af3, Bq[1][3], acc1, 0, 0, 0);
    acc2 = __builtin_amdgcn_mfma_i32_16x16x64_i8(Af3, Bq[2][3], acc2, 0, 0, 0);
    // ---- wave-local gate exchange (no barrier; same-wave DS is in-order) ----
    if (quad == 0) {     // C-layout rows 0..3 live in quad 0, col = m15
#pragma unroll
      for (int i = 0; i < 4; i++) {
        smGi[v][i * 16 + m15]       = acc0[i];
        smGi[v][64 + i * 16 + m15]  = acc1[i];
        smGi[v][128 + i * 16 + m15] = acc2[i];
      }
    }
    int igr = smGi[v][lane];          // row=quad, c=m15 -> quad*16+m15 = lane
    int igz = smGi[v][64 + lane];
    int ign = smGi[v][128 + lane];
    // ---- phase B: gates, 1 element/lane ----
    float r = fast_sigmoid(fmaf((float)igr, SCL, gic0 + bh[0]));
    float z = fast_sigmoid(fmaf((float)igz, SCL, gic1 + bh[1]));
    float n = fast_tanh(fmaf(r, fmaf((float)ign, SCL, bh[2]), gic2));
    float h = (1.f - z) * n + z * hprev;
    hprev = h;
    // h -> i8 LDS (swizzled layout) for next step
    int hq = (int)__builtin_rintf(h * 127.f);
    hb[(s + 1) & 1][wofs] = (char)hq;
    // buffer bf16 output (flushed at top of step s+1 when 8 accumulated)
    unsigned hb16 = (unsigned)(unsigned short)f2b(h);
    int idx = s & 7;
    if ((idx & 1) == 0) obuf[idx >> 1] = hb16;
    else                obuf[idx >> 1] |= hb16 << 16;
    gic0 = b2f(n0); gic1 = b2f(n1); gic2 = b2f(n2);
    __syncthreads();   // the one barrier: publishes hb[s+1]
  }
  // final flush (steps 504..511)
  {
    short* p = hflush;
#pragma unroll
    for (int k = 0; k < 8; k++) {
      *p = (short)(obuf[k >> 1] >> ((k & 1) * 16));
      p += hdelta;
    }
  }
}

// ---------------- residual + LayerNorm (ff input bf16; r8-verified form) ----------------
// FIRST=1: residual read from bf16 hcat16 (GRU output); else fp32 hres.
template <int FIRST>
__global__ __launch_bounds__(256) void k_ln(const float* __restrict__ hinf,
    const short* __restrict__ ff16, const float* __restrict__ gw,
    const float* __restrict__ bw, float* __restrict__ hout, short* __restrict__ h16) {
  int row = blockIdx.x * 4 + (threadIdx.x >> 6);
  int lane = threadIdx.x & 63;
  size_t base = (size_t)row * 512 + lane * 8;
  f32x4 x0, x1;
  if (FIRST) {
    short8 hv = *(const short8*)(h16 + base);
#pragma unroll
    for (int i = 0; i < 4; i++) { x0[i] = b2f(hv[i]); x1[i] = b2f(hv[4 + i]); }
  } else {
    x0 = *(const f32x4*)(hinf + base);
    x1 = *(const f32x4*)(hinf + base + 4);
  }
  short8 fv = *(const short8*)(ff16 + base);
#pragma unroll
  for (int i = 0; i < 4; i++) { x0[i] += b2f(fv[i]); x1[i] += b2f(fv[4 + i]); }
  float s = x0[0] + x0[1] + x0[2] + x0[3] + x1[0] + x1[1] + x1[2] + x1[3];
#pragma unroll
  for (int off = 32; off >= 1; off >>= 1) s += __shfl_xor(s, off);
  float mu = s * (1.f / 512.f);
  float vv = 0.f;
#pragma unroll
  for (int i = 0; i < 4; i++) { float d0 = x0[i] - mu, d1 = x1[i] - mu; vv += d0 * d0 + d1 * d1; }
#pragma unroll
  for (int off = 32; off >= 1; off >>= 1) vv += __shfl_xor(vv, off);
  float rs = rsqrtf(vv * (1.f / 512.f) + 1e-5f);
  int e = lane * 8;
  f32x4 g0 = *(const f32x4*)(gw + e), g1 = *(const f32x4*)(gw + e + 4);
  f32x4 bb0 = *(const f32x4*)(bw + e), bb1 = *(const f32x4*)(bw + e + 4);
  f32x4 o0, o1; short8 ob;
#pragma unroll
  for (int i = 0; i < 4; i++) {
    float a = (x0[i] - mu) * rs * g0[i] + bb0[i];
    float b = (x1[i] - mu) * rs * g1[i] + bb1[i];
    o0[i] = a; o1[i] = b; ob[i] = f2b(a); ob[4 + i] = f2b(b);
  }
  *(f32x4*)(hout + base) = o0;
  *(f32x4*)(hout + base + 4) = o1;
  *(short8*)(h16 + base) = ob;
}

// ---------------- final FC (N=16), fp32 weights ----------------
__global__ __launch_bounds__(256) void k_fc(const float* __restrict__ h,
    const float* __restrict__ fcw, const float* __restrict__ bias,
    float* __restrict__ logits) {
  int row = blockIdx.x * 4 + (threadIdx.x >> 6);
  int lane = threadIdx.x & 63;
  int c = lane & 15, part = lane >> 4;
  const float* ph = h + (size_t)row * 512 + part * 128;
  const float* pw = fcw + (size_t)part * 128 * 16 + c;
  float acc = 0.f;
#pragma unroll 8
  for (int k = 0; k < 128; k += 4) {
    f32x4 hv = *(const f32x4*)(ph + k);
    acc += hv[0] * pw[(k) * 16] + hv[1] * pw[(k + 1) * 16]
         + hv[2] * pw[(k + 2) * 16] + hv[3] * pw[(k + 3) * 16];
  }
  acc += __shfl_xor(acc, 16);
  acc += __shfl_xor(acc, 32);
  if (part == 0) logits[(size_t)row * 16 + c] = acc + bias[c];
}

// ---------------- CRF Viterbi v3: LDS-staged emissions (r9-verified) ----------------
__global__ __launch_bounds__(64) void k_crf(const float* __restrict__ logits,
    const int* __restrict__ y, const float* __restrict__ trans,
    float* __restrict__ out) {
  __shared__ float elds[512][16];          // 32 KB
  __shared__ int   yds[512];               // 2 KB
  __shared__ unsigned char bp[511][16];    // ~8 KB
  int b = blockIdx.x, lane = threadIdx.x;
  int cur = lane & 15, g = lane >> 4;
  // stage emissions: element (t,c) at logits[t*512 + b*16 + c]
  {
    const float* lg = logits + (size_t)b * 16;
    int t0 = lane >> 2, c4 = (lane & 3) * 4;
#pragma unroll 4
    for (int it = 0; it < 32; it++) {
      int t = t0 + it * 16;
      *(f32x4*)&elds[t][c4] = *(const f32x4*)(lg + (size_t)t * 512 + c4);
    }
    const int* yb = y + b * 512;
    for (int i = lane; i < 512; i += 64) yds[i] = yb[i];
  }
  float trr0 = trans[(4 * g + 0) * 16 + cur];
  float trr1 = trans[(4 * g + 1) * 16 + cur];
  float trr2 = trans[(4 * g + 2) * 16 + cur];
  float trr3 = trans[(4 * g + 3) * 16 + cur];
  __syncthreads();   // staging visible
  float score = trans[16 + cur] + elds[0][cur];    // tr[BOS=1][cur] + emit[0]
  for (int t = 1; t < 512; t++) {
    float s0 = __shfl(score, 4 * g + 0);
    float s1 = __shfl(score, 4 * g + 1);
    float s2 = __shfl(score, 4 * g + 2);
    float s3 = __shfl(score, 4 * g + 3);
    float best = s0 + trr0; int arg = 4 * g;
    float c1 = s1 + trr1; if (c1 > best) { best = c1; arg = 4 * g + 1; }
    float c2 = s2 + trr2; if (c2 > best) { best = c2; arg = 4 * g + 2; }
    float c3 = s3 + trr3; if (c3 > best) { best = c3; arg = 4 * g + 3; }
    // merge across g-pairs; lower-p side wins ties (matches ascending scan)
    float pv = __shfl_xor(best, 16); int pa = __shfl_xor(arg, 16);
    bool take = (lane & 16) ? (pv >= best) : (pv > best);
    if (take) { best = pv; arg = pa; }
    pv = __shfl_xor(best, 32); pa = __shfl_xor(arg, 32);
    take = (lane & 32) ? (pv >= best) : (pv > best);
    if (take) { best = pv; arg = pa; }
    if (lane < 16) bp[t - 1][cur] = (unsigned char)arg;
    float ns = best + elds[t][cur];
    if (yds[t] == 0) ns = score;
    score = ns;
  }
  score += trans[cur * 16 + 2];               // tr[cur][EOS=2]
  float best = -3.4e38f; int argb = 0;
#pragma unroll
  for (int p = 0; p < 16; p++) {
    float sp = __shfl(score, p);
    if (sp > best) { best = sp; argb = p; }
  }
  __syncthreads();
  if (lane == 0) {
    out[b] = best;
    float* po = out + 32 + (size_t)b * 512;
    int tag = argb;
    po[511] = (float)tag;
    for (int t = 511; t >= 1; t--) {
      int prev = bp[t - 1][tag];
      if (yds[t] == 0) prev = tag;
      po[t - 1] = (float)prev;
      tag = prev;
    }
  }
}

// ---------------- host ----------------
extern "C" void kernel_launch(void* const* d_in, const int* in_sizes, int n_in,
                              void* d_out, int out_size, void* d_ws, size_t ws_size,
                              hipStream_t stream) {
  const int*   x      = (const int*)d_in[0];
  const int*   y      = (const int*)d_in[1];
  const float* embedW = (const float*)d_in[2];
  const float* w_ih_f = (const float*)d_in[3];
  const float* w_hh_f = (const float*)d_in[4];
  const float* b_ih_f = (const float*)d_in[5];
  const float* b_hh_f = (const float*)d_in[6];
  const float* w_ih_b = (const float*)d_in[7];
  const float* w_hh_b = (const float*)d_in[8];
  const float* b_ih_b = (const float*)d_in[9];
  const float* b_hh_b = (const float*)d_in[10];
  const float* ff_w1  = (const float*)d_in[11];
  const float* ff_b1  = (const float*)d_in[12];
  const float* ff_w2  = (const float*)d_in[13];
  const float* ff_b2  = (const float*)d_in[14];
  const float* ln_g   = (const float*)d_in[15];
  const float* ln_b   = (const float*)d_in[16];
  const float* fc_w   = (const float*)d_in[17];
  const float* fc_b   = (const float*)d_in[18];
  const float* trans  = (const float*)d_in[19];
  float* out = (float*)d_out;

  char* ws = (char*)d_ws;
  short* h0     = (short*)(ws + 0);                 // 16.78 MB bf16 (B,T,E)
  short* gi16   = (short*)(ws + 16777216);          // 50.33 MB bf16 [t][b][1536] (f|b)
  short* mid    = (short*)(ws + 16777216);          // 67.1 MB bf16, overlays gi16 (dead after GRU)
  float* pe     = (float*)(ws + 83886080);          // 1 MB PE table (dead after k_embed...)
  short* ffout16= (short*)(ws + 83886080);          // ...overlaid by 16.78 MB bf16 FF output
  short* wihf16 = (short*)(ws + 117440512);         // bf16 (768,512); wihb16 contiguous after
  short* wihb16 = (short*)(ws + 118226944);         //   -> combined (1536,512) B matrix
  int*   wq8    = (int*)  (ws + 119013376);         // i8 frags, 393216 B
  short* w1t    = (short*)(ws + 119799808);         // bf16 (4 x 2048x512)
  short* w2t    = (short*)(ws + 128188416);         // bf16 (4 x 512x2048)
  short* hcat16 = (short*)(ws + 136577024);         // bf16 [t][b][512]
  float* hres   = (float*)(ws + 153354240);         // fp32 residual [t][b][512]
  float* logits = (float*)(ws + 186908672);         // fp32 [t][b][16]

  k_pe<<<512, 256, 0, stream>>>(pe);
  k_embed<<<4096, 256, 0, stream>>>(x, embedW, pe, h0);
  k_cvt2<<<768, 256, 0, stream>>>(w_ih_f, w_ih_b, wihf16, wihb16);
  k_wq8<<<96, 256, 0, stream>>>(w_hh_f, w_hh_b, wq8);

  // merged ih-projection: A(16384,512) x B(1536,512)^T -> gi16 [t][b][1536]
  k_gemm<3><<<1536, 256, 0, stream>>>(h0, wihf16, b_ih_f, b_ih_b, nullptr, gi16, 16384, 1536, 512);

  // GRU (blocks 0..15) + folded ff_w1/ff_w2 transpose (blocks 16..2063)
  k_gru<<<2064, 1024, 0, stream>>>(wq8, b_hh_f, b_hh_b, gi16, hcat16,
                                   ff_w1, ff_w2, w1t, w2t);

  for (int i = 0; i < 4; i++) {
    k_gemm<1><<<2048, 256, 0, stream>>>(hcat16, w1t + (size_t)i * 1048576, ff_b1 + i * 2048,
                                        nullptr, nullptr, mid, 16384, 2048, 512);
    k_gemm<4><<<512, 256, 0, stream>>>(mid, w2t + (size_t)i * 1048576, ff_b2 + i * 512,
                                       nullptr, nullptr, ffout16, 16384, 512, 2048);
    if (i == 0)
      k_ln<1><<<4096, 256, 0, stream>>>(nullptr, ffout16, ln_g, ln_b, hres, hcat16);
    else
      k_ln<0><<<4096, 256, 0, stream>>>(hres, ffout16, ln_g + i * 512, ln_b + i * 512, hres, hcat16);
  }
  k_fc<<<4096, 256, 0, stream>>>(hres, fc_w, fc_b, logits);
  k_crf<<<32, 64, 0, stream>>>(logits, y, trans, out);
}